// Round 6
// baseline (310.087 us; speedup 1.0000x reference)
//
#include <hip/hip_runtime.h>

// Problem constants
#define DIMD   256
#define NTOK   16384
#define NCODE  8192
#define NELEM  (NTOK * DIMD)

// fp32 project-GEMM tiling
#define BM 128
#define BK 128
#define BD 32
#define PAD 4
#define LDS_STRIDE (BM + PAD)

// distance kernels — two-pass design.
// Round-1 lesson: never force launch_bounds min-waves up (spills; true
//   footprint ~256 regs/wave incl A-frags -> 2 waves/SIMD).
// Round-2 lesson (rule #20): never runtime-index acc[] (LDS demotion).
// Round-4/5 lesson: device-scope same-address atomics in the hot loop
//   serialize the device (425us); LDS staging + 1 global atomic/block is
//   the only safe emission (83us). CONFIRMED by within-problem A/B.
// Round-6 change: split lo/hi accumulator chains (8 indep MFMA chains,
//   dep distance 8 insts) to cover MFMA latency at 2 waves/SIMD; fuse
//   cnorm into project epilogue; merge memsets (11 -> 9 dispatches).
#define SPLITS_B 4                    // grid.y code splits (1024 blocks total)
#define CODES_PER_WAVE (NCODE / SPLITS_B / 4)   // 512
#define NGROUPS (CODES_PER_WAVE / 16)           // 32
#define MARGIN 0.5f                   // > two-sided worst-case bf16 distance error
#define EBUF_CAP 1024                 // per-block emit staging (expected ~32 hits)

typedef float floatx4 __attribute__((ext_vector_type(4)));
typedef short short8  __attribute__((ext_vector_type(8)));

__device__ __forceinline__ unsigned short f2bf(float f) {
    unsigned u = __float_as_uint(f);
    unsigned r = (u + 0x7FFFu + ((u >> 16) & 1u)) >> 16;
    return (unsigned short)r;
}

// monotone float<->uint key (handles negative partial distances)
__device__ __forceinline__ unsigned fkey(float f) {
    unsigned u = __float_as_uint(f);
    return (u & 0x80000000u) ? ~u : (u | 0x80000000u);
}
__device__ __forceinline__ float funkey(unsigned k) {
    unsigned u = (k & 0x80000000u) ? (k & 0x7FFFFFFFu) : ~k;
    return __uint_as_float(u);
}

// fragment-major Cb index for element (row=code, col=k):
// block (row/16, col/32) of 512 elems; within: lane=(colsub/8)*16+(row%16), elem=col%8
__device__ __forceinline__ size_t cb2_idx(int row, int col) {
    return ((size_t)((row >> 4) * 8 + (col >> 5))) * 512
         + (size_t)((((col >> 3) & 3) * 16 + (row & 15)) * 8 + (col & 7));
}

// -------------------------------------------------------------------------
// Kernel 1: codebook projection C = E @ W^T + b (fp32) + fragment-major
// bf16 copy Cb2 + FUSED cnorm (block-local LDS reduce -> 2 commutative
// fp32 atomicAdds per row; exact and order-independent for 2 partials).
// -------------------------------------------------------------------------
__global__ __launch_bounds__(256, 3)
void project_kernel(const float* __restrict__ E, const float* __restrict__ W,
                    const float* __restrict__ bias, float* __restrict__ C,
                    unsigned short* __restrict__ Cb2, float* __restrict__ cnorm)
{
    __shared__ float smem[2 * BD * LDS_STRIDE];
    float* As = smem;
    float* Bs = smem + BD * LDS_STRIDE;

    const int tid = threadIdx.x;
    const int tx  = tid & 15;
    const int ty  = tid >> 4;
    const int m0  = blockIdx.x * BM;
    const int j0  = blockIdx.y * BK;

    const int srow = tid >> 3;
    const int scol = (tid & 7) * 4;

    float acc[8][8];
#pragma unroll
    for (int i = 0; i < 8; ++i)
#pragma unroll
        for (int j = 0; j < 8; ++j) acc[i][j] = 0.f;

    for (int dc = 0; dc < DIMD / BD; ++dc) {
        const int d0 = dc * BD;
        __syncthreads();
#pragma unroll
        for (int rr = 0; rr < 4; ++rr) {
            const int r = srow + rr * 32;
            float4 av = *(const float4*)&E[(size_t)(m0 + r) * DIMD + d0 + scol];
            As[(scol + 0) * LDS_STRIDE + r] = av.x;
            As[(scol + 1) * LDS_STRIDE + r] = av.y;
            As[(scol + 2) * LDS_STRIDE + r] = av.z;
            As[(scol + 3) * LDS_STRIDE + r] = av.w;
            float4 bv = *(const float4*)&W[(size_t)(j0 + r) * DIMD + d0 + scol];
            Bs[(scol + 0) * LDS_STRIDE + r] = bv.x;
            Bs[(scol + 1) * LDS_STRIDE + r] = bv.y;
            Bs[(scol + 2) * LDS_STRIDE + r] = bv.z;
            Bs[(scol + 3) * LDS_STRIDE + r] = bv.w;
        }
        __syncthreads();
#pragma unroll 4
        for (int d = 0; d < BD; ++d) {
            float4 a0 = *(float4*)&As[d * LDS_STRIDE + ty * 4];
            float4 a1 = *(float4*)&As[d * LDS_STRIDE + 64 + ty * 4];
            float4 b0 = *(float4*)&Bs[d * LDS_STRIDE + tx * 4];
            float4 b1 = *(float4*)&Bs[d * LDS_STRIDE + 64 + tx * 4];
            float a[8] = {a0.x, a0.y, a0.z, a0.w, a1.x, a1.y, a1.z, a1.w};
            float b[8] = {b0.x, b0.y, b0.z, b0.w, b1.x, b1.y, b1.z, b1.w};
#pragma unroll
            for (int i = 0; i < 8; ++i)
#pragma unroll
                for (int j = 0; j < 8; ++j) acc[i][j] = fmaf(a[i], b[j], acc[i][j]);
        }
    }

    // epilogue: bias, stores, and per-row |c|^2 partials into LDS
    __syncthreads();                       // done reading As/Bs; reuse smem
    float* red = smem;                     // [128 rows][16 tx] partials

    float4 bja = *(const float4*)&bias[j0 + tx * 4];
    float4 bjb = *(const float4*)&bias[j0 + 64 + tx * 4];
#pragma unroll
    for (int i = 0; i < 8; ++i) {
        const int mloc = (i < 4) ? (ty * 4 + i) : (64 + ty * 4 + (i - 4));
        const int row  = m0 + mloc;
        const size_t rbase = (size_t)row * DIMD;
        float o[8] = {acc[i][0] + bja.x, acc[i][1] + bja.y, acc[i][2] + bja.z, acc[i][3] + bja.w,
                      acc[i][4] + bjb.x, acc[i][5] + bjb.y, acc[i][6] + bjb.z, acc[i][7] + bjb.w};
        *(float4*)&C[rbase + j0 + tx * 4]      = *(float4*)&o[0];
        *(float4*)&C[rbase + j0 + 64 + tx * 4] = *(float4*)&o[4];
        ushort4 h0 = {f2bf(o[0]), f2bf(o[1]), f2bf(o[2]), f2bf(o[3])};
        ushort4 h1 = {f2bf(o[4]), f2bf(o[5]), f2bf(o[6]), f2bf(o[7])};
        *(ushort4*)&Cb2[cb2_idx(row, j0 + tx * 4)]      = h0;
        *(ushort4*)&Cb2[cb2_idx(row, j0 + 64 + tx * 4)] = h1;
        float p = 0.f;
#pragma unroll
        for (int j = 0; j < 8; ++j) p = fmaf(o[j], o[j], p);
        red[mloc * 16 + tx] = p;
    }
    __syncthreads();
    if (tid < 128) {
        float s = 0.f;
#pragma unroll
        for (int k = 0; k < 16; ++k) s += red[tid * 16 + k];
        atomicAdd(&cnorm[m0 + tid], s);    // 2 contributions/row, commutative
    }
}

// -------------------------------------------------------------------------
// Kernel 2: X -> xnorm + bf16 Xb (row-major; A-loads are once per wave).
// -------------------------------------------------------------------------
__global__ void convx_kernel(const float* __restrict__ X, float* __restrict__ xnorm,
                             unsigned short* __restrict__ Xb)
{
    const int wave = threadIdx.x >> 6;
    const int lane = threadIdx.x & 63;
    const int row  = blockIdx.x * 4 + wave;
    float4 v = *(const float4*)&X[(size_t)row * DIMD + lane * 4];
    ushort4 h = {f2bf(v.x), f2bf(v.y), f2bf(v.z), f2bf(v.w)};
    *(ushort4*)&Xb[(size_t)row * DIMD + lane * 4] = h;
    float s = v.x * v.x + v.y * v.y + v.z * v.z + v.w * v.w;
#pragma unroll
    for (int off = 1; off < 64; off <<= 1) s += __shfl_xor(s, off);
    if (lane == 0) xnorm[row] = s;
}

// -------------------------------------------------------------------------
// Kernel 3a: PASS 1 — pure min-GEMM with SPLIT lo/hi accumulator chains
// (8 independent MFMA chains, dep distance 8 insts, covers MFMA latency
// at 2 waves/SIMD). One 16-lane reduce + block combine at the end, then
// one global atomicMin per token (monotone key, distinct addresses).
// -------------------------------------------------------------------------
__global__ __launch_bounds__(256, 2)
void dist_min_kernel(const unsigned short* __restrict__ Xb,
                     const unsigned short* __restrict__ Cb2,
                     const float* __restrict__ cnorm,
                     unsigned* __restrict__ minkey)
{
    __shared__ float wmin[4][64];

    const int tid  = threadIdx.x;
    const int lane = tid & 63;
    const int wv   = tid >> 6;
    const int l15  = lane & 15;
    const int quad = lane >> 4;
    const int tok0 = blockIdx.x * 64;
    const int cbase = blockIdx.y * (NCODE / SPLITS_B) + wv * CODES_PER_WAVE;

    // A fragments: 64 tokens x 256 k, register-resident (128 regs)
    short8 a[4][8];
#pragma unroll
    for (int i = 0; i < 4; ++i) {
        const unsigned short* ap = Xb + (size_t)(tok0 + i * 16 + l15) * DIMD + quad * 8;
#pragma unroll
        for (int ks = 0; ks < 8; ++ks)
            a[i][ks] = *(const short8*)(ap + ks * 32);
    }

    float runv[16];
#pragma unroll
    for (int s = 0; s < 16; ++s) runv[s] = 3.4e38f;

    const unsigned short* bp0 = Cb2 + (size_t)cbase * DIMD + lane * 8;

    short8 breg[2][8];
    float  cnr[2];
#pragma unroll
    for (int ks = 0; ks < 8; ++ks) breg[0][ks] = *(const short8*)(bp0 + ks * 512);
    cnr[0] = cnorm[cbase + l15];

    auto group_body = [&](int g, short8 (&bc)[8], short8 (&bn)[8],
                          float cnc, float& cnn) {
        if (g + 1 < NGROUPS) {
            const unsigned short* bpn = bp0 + (size_t)(g + 1) * 4096;
#pragma unroll
            for (int ks = 0; ks < 8; ++ks) bn[ks] = *(const short8*)(bpn + ks * 512);
            cnn = cnorm[cbase + (g + 1) * 16 + l15];
        }

        floatx4 alo[4], ahi[4];
#pragma unroll
        for (int i = 0; i < 4; ++i) {
            alo[i] = (floatx4){0.f, 0.f, 0.f, 0.f};
            ahi[i] = (floatx4){0.f, 0.f, 0.f, 0.f};
        }
#pragma unroll
        for (int ks = 0; ks < 8; ks += 2) {
#pragma unroll
            for (int i = 0; i < 4; ++i)
                alo[i] = __builtin_amdgcn_mfma_f32_16x16x32_bf16(a[i][ks], bc[ks], alo[i], 0, 0, 0);
#pragma unroll
            for (int i = 0; i < 4; ++i)
                ahi[i] = __builtin_amdgcn_mfma_f32_16x16x32_bf16(a[i][ks + 1], bc[ks + 1], ahi[i], 0, 0, 0);
        }

#pragma unroll
        for (int i = 0; i < 4; ++i)
#pragma unroll
            for (int r = 0; r < 4; ++r)
                runv[i * 4 + r] = fminf(runv[i * 4 + r],
                                        fmaf(-2.f, alo[i][r] + ahi[i][r], cnc));
    };

    for (int gg = 0; gg < NGROUPS; gg += 2) {
        group_body(gg,     breg[0], breg[1], cnr[0], cnr[1]);
        group_body(gg + 1, breg[1], breg[0], cnr[1], cnr[0]);
    }

    // end-of-kernel reduce: min over this wave's 16 code-lanes
#pragma unroll
    for (int s = 0; s < 16; ++s) {
        float m = runv[s];
#pragma unroll
        for (int off = 1; off < 16; off <<= 1) m = fminf(m, __shfl_xor(m, off));
        runv[s] = m;
    }
    if (l15 == 0) {
#pragma unroll
        for (int i = 0; i < 4; ++i)
#pragma unroll
            for (int r = 0; r < 4; ++r)
                wmin[wv][i * 16 + quad * 4 + r] = runv[i * 4 + r];
    }
    __syncthreads();
    if (tid < 64) {
        const float bm = fminf(fminf(wmin[0][tid], wmin[1][tid]),
                               fminf(wmin[2][tid], wmin[3][tid]));
        atomicMin(&minkey[tok0 + tid], fkey(bm));
    }
}

// -------------------------------------------------------------------------
// Kernel 3b: PASS 2 — recompute distances (same split-chain order as pass
// 1) vs the FINAL global per-token threshold. Rare hits staged in a
// block-local LDS buffer (LDS atomicAdd only); ONE device-scope atomic per
// block appends the staged entries to the global list at the end.
// -------------------------------------------------------------------------
__global__ __launch_bounds__(256, 2)
void dist_emit_kernel(const unsigned short* __restrict__ Xb,
                      const unsigned short* __restrict__ Cb2,
                      const float* __restrict__ cnorm,
                      const unsigned* __restrict__ minkey,
                      unsigned* __restrict__ list, unsigned* __restrict__ count,
                      unsigned cap)
{
    __shared__ float tokthr[64];
    __shared__ unsigned ebuf[EBUF_CAP];
    __shared__ unsigned ecnt, gbase;

    const int tid  = threadIdx.x;
    const int lane = tid & 63;
    const int wv   = tid >> 6;
    const int l15  = lane & 15;
    const int quad = lane >> 4;
    const int tok0 = blockIdx.x * 64;
    const int cbase = blockIdx.y * (NCODE / SPLITS_B) + wv * CODES_PER_WAVE;

    if (tid == 0) ecnt = 0;
    if (tid < 64) tokthr[tid] = funkey(minkey[tok0 + tid]) + MARGIN;
    __syncthreads();

    short8 a[4][8];
#pragma unroll
    for (int i = 0; i < 4; ++i) {
        const unsigned short* ap = Xb + (size_t)(tok0 + i * 16 + l15) * DIMD + quad * 8;
#pragma unroll
        for (int ks = 0; ks < 8; ++ks)
            a[i][ks] = *(const short8*)(ap + ks * 32);
    }

    // fixed per-slot thresholds in registers (static indexing only)
    float thr[16];
#pragma unroll
    for (int i = 0; i < 4; ++i)
#pragma unroll
        for (int r = 0; r < 4; ++r)
            thr[i * 4 + r] = tokthr[i * 16 + quad * 4 + r];

    const unsigned short* bp0 = Cb2 + (size_t)cbase * DIMD + lane * 8;

    short8 breg[2][8];
    float  cnr[2];
#pragma unroll
    for (int ks = 0; ks < 8; ++ks) breg[0][ks] = *(const short8*)(bp0 + ks * 512);
    cnr[0] = cnorm[cbase + l15];

    auto group_body = [&](int g, short8 (&bc)[8], short8 (&bn)[8],
                          float cnc, float& cnn) {
        const int code0 = cbase + g * 16;
        if (g + 1 < NGROUPS) {
            const unsigned short* bpn = bp0 + (size_t)(g + 1) * 4096;
#pragma unroll
            for (int ks = 0; ks < 8; ++ks) bn[ks] = *(const short8*)(bpn + ks * 512);
            cnn = cnorm[code0 + 16 + l15];
        }

        floatx4 alo[4], ahi[4];
#pragma unroll
        for (int i = 0; i < 4; ++i) {
            alo[i] = (floatx4){0.f, 0.f, 0.f, 0.f};
            ahi[i] = (floatx4){0.f, 0.f, 0.f, 0.f};
        }
#pragma unroll
        for (int ks = 0; ks < 8; ks += 2) {
#pragma unroll
            for (int i = 0; i < 4; ++i)
                alo[i] = __builtin_amdgcn_mfma_f32_16x16x32_bf16(a[i][ks], bc[ks], alo[i], 0, 0, 0);
#pragma unroll
            for (int i = 0; i < 4; ++i)
                ahi[i] = __builtin_amdgcn_mfma_f32_16x16x32_bf16(a[i][ks + 1], bc[ks + 1], ahi[i], 0, 0, 0);
        }

        unsigned mask = 0;
        float dv[16];
#pragma unroll
        for (int i = 0; i < 4; ++i)
#pragma unroll
            for (int r = 0; r < 4; ++r) {
                const int s = i * 4 + r;
                dv[s] = fmaf(-2.f, alo[i][r] + ahi[i][r], cnc);
                if (dv[s] < thr[s]) mask |= (1u << s);
            }

        if (__any(mask != 0)) {
            if (mask) {
                unsigned pos = atomicAdd(&ecnt, (unsigned)__popc(mask));
#pragma unroll
                for (int i = 0; i < 4; ++i)
#pragma unroll
                    for (int r = 0; r < 4; ++r) {
                        const int s = i * 4 + r;
                        if (mask & (1u << s)) {
                            const unsigned token = tok0 + i * 16 + quad * 4 + r;
                            const unsigned entry = (token << 13) | (unsigned)(code0 + l15);
                            if (pos < EBUF_CAP) ebuf[pos] = entry;
                            else { unsigned gp = atomicAdd(count, 1u); if (gp < cap) list[gp] = entry; }
                            ++pos;
                        }
                    }
            }
        }
    };

    for (int gg = 0; gg < NGROUPS; gg += 2) {
        group_body(gg,     breg[0], breg[1], cnr[0], cnr[1]);
        group_body(gg + 1, breg[1], breg[0], cnr[1], cnr[0]);
    }

    __syncthreads();
    const unsigned n = (ecnt < EBUF_CAP) ? ecnt : EBUF_CAP;
    if (tid == 0) gbase = atomicAdd(count, n);
    __syncthreads();
    const unsigned gb = gbase;
    for (unsigned i = tid; i < n; i += 256) {
        const unsigned p = gb + i;
        if (p < cap) list[p] = ebuf[i];
    }
}

// -------------------------------------------------------------------------
// Kernel 4: exact fp32 rescore. 16-lane groups, 4 candidates per wave.
// Packed (d_bits<<32 | code) atomicMin -> lowest-index tie-break.
// -------------------------------------------------------------------------
__global__ __launch_bounds__(256)
void rescore_kernel(const float* __restrict__ X, const float* __restrict__ C,
                    const float* __restrict__ xnorm, const float* __restrict__ cnorm,
                    const unsigned* __restrict__ list, const unsigned* __restrict__ count,
                    unsigned cap, unsigned long long* __restrict__ fin)
{
    const int lane = threadIdx.x & 63;
    const int g16  = lane & 15;
    const int sub  = lane >> 4;
    const int gid  = ((blockIdx.x * 256 + threadIdx.x) >> 6) * 4 + sub;
    const int ng   = ((gridDim.x * 256) >> 6) * 4;
    unsigned n = *count; if (n > cap) n = cap;

    for (unsigned c = gid; c < n; c += ng) {
        const unsigned e = list[c];
        const unsigned tok = e >> 13, code = e & 8191u;
        const float* xr = &X[(size_t)tok * DIMD];
        const float* cr = &C[(size_t)code * DIMD];
        float dot = 0.f;
#pragma unroll
        for (int r = 0; r < 4; ++r) {
            float4 x4 = *(const float4*)&xr[r * 64 + g16 * 4];
            float4 c4 = *(const float4*)&cr[r * 64 + g16 * 4];
            dot = fmaf(x4.x, c4.x, dot);
            dot = fmaf(x4.y, c4.y, dot);
            dot = fmaf(x4.z, c4.z, dot);
            dot = fmaf(x4.w, c4.w, dot);
        }
#pragma unroll
        for (int d = 1; d < 16; d <<= 1) dot += __shfl_xor(dot, d);
        if (g16 == 0) {
            const float dd = xnorm[tok] + cnorm[code] - 2.f * dot;
            const unsigned long long p =
                ((unsigned long long)__float_as_uint(dd) << 32) | code;
            atomicMin(&fin[tok], p);
        }
    }
}

// -------------------------------------------------------------------------
// Kernel 5: gather winner, straight-through output, loss. One atomic/block.
// -------------------------------------------------------------------------
__global__ __launch_bounds__(256)
void finalize_kernel(const float* __restrict__ X, const float* __restrict__ C,
                     const unsigned long long* __restrict__ fin,
                     float* __restrict__ out)
{
    __shared__ float part[4];
    const int lane = threadIdx.x & 63;
    const int wv   = threadIdx.x >> 6;
    const int t0   = blockIdx.x * 64;

    float local = 0.f;
    for (int it = 0; it < 16; ++it) {
        const int t = t0 + wv * 16 + it;
        const unsigned code = (unsigned)(fin[t] & 0xFFFFFFFFull);
        float4 c4 = *(const float4*)&C[(size_t)code * DIMD + lane * 4];
        float4 x4 = *(const float4*)&X[(size_t)t * DIMD + lane * 4];
        float4 w  = {c4.x - x4.x, c4.y - x4.y, c4.z - x4.z, c4.w - x4.w};
        local += w.x * w.x + w.y * w.y + w.z * w.z + w.w * w.w;
        float4 zq = {x4.x + w.x, x4.y + w.y, x4.z + w.z, x4.w + w.w};
        *(float4*)&out[(size_t)t * DIMD + lane * 4] = zq;
        if (lane == 0) out[NELEM + 1 + t] = (float)code;
    }
#pragma unroll
    for (int off = 1; off < 64; off <<= 1) local += __shfl_xor(local, off);
    if (lane == 0) part[wv] = local;
    __syncthreads();
    if (threadIdx.x == 0) {
        const float s = part[0] + part[1] + part[2] + part[3];
        atomicAdd(&out[NELEM], s * (1.25f / (float)NELEM));
    }
}

// -------------------------------------------------------------------------
extern "C" void kernel_launch(void* const* d_in, const int* in_sizes, int n_in,
                              void* d_out, int out_size, void* d_ws, size_t ws_size,
                              hipStream_t stream)
{
    const float* X = (const float*)d_in[0];
    const float* E = (const float*)d_in[1];
    const float* W = (const float*)d_in[2];
    const float* b = (const float*)d_in[3];
    float* out = (float*)d_out;

    char* w = (char*)d_ws;
    float* C            = (float*)w;           w += (size_t)NCODE * DIMD * 4;
    unsigned short* Xb  = (unsigned short*)w;  w += (size_t)NTOK * DIMD * 2;
    unsigned short* Cb2 = (unsigned short*)w;  w += (size_t)NCODE * DIMD * 2;
    float* xnorm        = (float*)w;           w += (size_t)NTOK * 4;
    // zero-group: cnorm + cnt adjacent -> one memset(0)
    float* cnorm        = (float*)w;           w += (size_t)NCODE * 4;
    unsigned* cnt       = (unsigned*)w;        w += 256;
    // 0xFF-group: fin + minkey adjacent -> one memset(0xFF)
    unsigned long long* fin = (unsigned long long*)w; w += (size_t)NTOK * 8;
    unsigned* minkey    = (unsigned*)w;        w += (size_t)NTOK * 4;
    unsigned* list      = (unsigned*)w;

    size_t used = (size_t)(w - (char*)d_ws);
    size_t avail = (ws_size > used) ? (ws_size - used) / 4 : 0;
    unsigned cap = (unsigned)((avail > 16777216u) ? 16777216u : avail);

    hipMemsetAsync(cnorm, 0, (size_t)NCODE * 4 + 256, stream);
    hipMemsetAsync(fin, 0xFF, (size_t)NTOK * 8 + (size_t)NTOK * 4, stream);
    hipMemsetAsync(out + NELEM, 0, 4, stream);

    project_kernel<<<dim3(NCODE / BM, DIMD / BK), 256, 0, stream>>>(E, W, b, C, Cb2, cnorm);
    convx_kernel<<<NTOK / 4, 256, 0, stream>>>(X, xnorm, Xb);
    dist_min_kernel<<<dim3(NTOK / 64, SPLITS_B), 256, 0, stream>>>(
        Xb, Cb2, cnorm, minkey);
    dist_emit_kernel<<<dim3(NTOK / 64, SPLITS_B), 256, 0, stream>>>(
        Xb, Cb2, cnorm, minkey, list, cnt, cap);
    rescore_kernel<<<1024, 256, 0, stream>>>(X, C, xnorm, cnorm, list, cnt, cap, fin);
    finalize_kernel<<<NTOK / 64, 256, 0, stream>>>(X, C, fin, out);
}

// Round 7
// 306.284 us; speedup vs baseline: 1.0124x; 1.0124x over previous
//
#include <hip/hip_runtime.h>

// Problem constants
#define DIMD   256
#define NTOK   16384
#define NCODE  8192
#define NELEM  (NTOK * DIMD)

// fp32 project-GEMM tiling
#define BM 128
#define BK 128
#define BD 32
#define PAD 4
#define LDS_STRIDE (BM + PAD)

// distance kernels — two-pass design.
// Round-1 lesson: never force launch_bounds min-waves up (spills).
// Round-2 lesson (rule #20): never runtime-index acc[] (LDS demotion).
// Round-4/5 lesson: device-scope same-address atomics in the hot loop
//   serialize the device (425us); LDS staging + 1 global atomic/block only.
// Round-6 lesson: dist kernels sit exactly at the 2-waves/SIMD register
//   wall (~250 true regs incl fragments); +16 regs (split acc chains)
//   -> spills (WRITE_SIZE 221KB -> 16.6MB, emit 83 -> 94us). Reverted.
// Round-7 experiment: dist_min restructured to 32 tokens/wave (A-frags
//   128 -> 64 VGPRs, est. total ~165 < 170-reg 3-waves/SIMD step);
//   dist_emit kept at the round-5 64-token form as same-run control.
#define SPLITS_B 4                    // grid.y code splits
#define CODES_PER_WAVE (NCODE / SPLITS_B / 4)   // 512
#define NGROUPS (CODES_PER_WAVE / 16)           // 32
#define MARGIN 0.5f                   // > two-sided worst-case bf16 distance error
#define EBUF_CAP 1024                 // per-block emit staging (expected ~32 hits)

typedef float floatx4 __attribute__((ext_vector_type(4)));
typedef short short8  __attribute__((ext_vector_type(8)));

__device__ __forceinline__ unsigned short f2bf(float f) {
    unsigned u = __float_as_uint(f);
    unsigned r = (u + 0x7FFFu + ((u >> 16) & 1u)) >> 16;
    return (unsigned short)r;
}

// monotone float<->uint key (handles negative partial distances)
__device__ __forceinline__ unsigned fkey(float f) {
    unsigned u = __float_as_uint(f);
    return (u & 0x80000000u) ? ~u : (u | 0x80000000u);
}
__device__ __forceinline__ float funkey(unsigned k) {
    unsigned u = (k & 0x80000000u) ? (k & 0x7FFFFFFFu) : ~k;
    return __uint_as_float(u);
}

// fragment-major Cb index for element (row=code, col=k):
// block (row/16, col/32) of 512 elems; within: lane=(colsub/8)*16+(row%16), elem=col%8
__device__ __forceinline__ size_t cb2_idx(int row, int col) {
    return ((size_t)((row >> 4) * 8 + (col >> 5))) * 512
         + (size_t)((((col >> 3) & 3) * 16 + (row & 15)) * 8 + (col & 7));
}

// -------------------------------------------------------------------------
// Kernel 1: codebook projection C = E @ W^T + b (fp32) + fragment-major
// bf16 copy Cb2 + FUSED cnorm (block-local LDS reduce -> 2 commutative
// fp32 atomicAdds per row; exact for 2 partials).
// -------------------------------------------------------------------------
__global__ __launch_bounds__(256, 3)
void project_kernel(const float* __restrict__ E, const float* __restrict__ W,
                    const float* __restrict__ bias, float* __restrict__ C,
                    unsigned short* __restrict__ Cb2, float* __restrict__ cnorm)
{
    __shared__ float smem[2 * BD * LDS_STRIDE];
    float* As = smem;
    float* Bs = smem + BD * LDS_STRIDE;

    const int tid = threadIdx.x;
    const int tx  = tid & 15;
    const int ty  = tid >> 4;
    const int m0  = blockIdx.x * BM;
    const int j0  = blockIdx.y * BK;

    const int srow = tid >> 3;
    const int scol = (tid & 7) * 4;

    float acc[8][8];
#pragma unroll
    for (int i = 0; i < 8; ++i)
#pragma unroll
        for (int j = 0; j < 8; ++j) acc[i][j] = 0.f;

    for (int dc = 0; dc < DIMD / BD; ++dc) {
        const int d0 = dc * BD;
        __syncthreads();
#pragma unroll
        for (int rr = 0; rr < 4; ++rr) {
            const int r = srow + rr * 32;
            float4 av = *(const float4*)&E[(size_t)(m0 + r) * DIMD + d0 + scol];
            As[(scol + 0) * LDS_STRIDE + r] = av.x;
            As[(scol + 1) * LDS_STRIDE + r] = av.y;
            As[(scol + 2) * LDS_STRIDE + r] = av.z;
            As[(scol + 3) * LDS_STRIDE + r] = av.w;
            float4 bv = *(const float4*)&W[(size_t)(j0 + r) * DIMD + d0 + scol];
            Bs[(scol + 0) * LDS_STRIDE + r] = bv.x;
            Bs[(scol + 1) * LDS_STRIDE + r] = bv.y;
            Bs[(scol + 2) * LDS_STRIDE + r] = bv.z;
            Bs[(scol + 3) * LDS_STRIDE + r] = bv.w;
        }
        __syncthreads();
#pragma unroll 4
        for (int d = 0; d < BD; ++d) {
            float4 a0 = *(float4*)&As[d * LDS_STRIDE + ty * 4];
            float4 a1 = *(float4*)&As[d * LDS_STRIDE + 64 + ty * 4];
            float4 b0 = *(float4*)&Bs[d * LDS_STRIDE + tx * 4];
            float4 b1 = *(float4*)&Bs[d * LDS_STRIDE + 64 + tx * 4];
            float a[8] = {a0.x, a0.y, a0.z, a0.w, a1.x, a1.y, a1.z, a1.w};
            float b[8] = {b0.x, b0.y, b0.z, b0.w, b1.x, b1.y, b1.z, b1.w};
#pragma unroll
            for (int i = 0; i < 8; ++i)
#pragma unroll
                for (int j = 0; j < 8; ++j) acc[i][j] = fmaf(a[i], b[j], acc[i][j]);
        }
    }

    // epilogue: bias, stores, and per-row |c|^2 partials into LDS
    __syncthreads();                       // done reading As/Bs; reuse smem
    float* red = smem;                     // [128 rows][16 tx] partials

    float4 bja = *(const float4*)&bias[j0 + tx * 4];
    float4 bjb = *(const float4*)&bias[j0 + 64 + tx * 4];
#pragma unroll
    for (int i = 0; i < 8; ++i) {
        const int mloc = (i < 4) ? (ty * 4 + i) : (64 + ty * 4 + (i - 4));
        const int row  = m0 + mloc;
        const size_t rbase = (size_t)row * DIMD;
        float o[8] = {acc[i][0] + bja.x, acc[i][1] + bja.y, acc[i][2] + bja.z, acc[i][3] + bja.w,
                      acc[i][4] + bjb.x, acc[i][5] + bjb.y, acc[i][6] + bjb.z, acc[i][7] + bjb.w};
        *(float4*)&C[rbase + j0 + tx * 4]      = *(float4*)&o[0];
        *(float4*)&C[rbase + j0 + 64 + tx * 4] = *(float4*)&o[4];
        ushort4 h0 = {f2bf(o[0]), f2bf(o[1]), f2bf(o[2]), f2bf(o[3])};
        ushort4 h1 = {f2bf(o[4]), f2bf(o[5]), f2bf(o[6]), f2bf(o[7])};
        *(ushort4*)&Cb2[cb2_idx(row, j0 + tx * 4)]      = h0;
        *(ushort4*)&Cb2[cb2_idx(row, j0 + 64 + tx * 4)] = h1;
        float p = 0.f;
#pragma unroll
        for (int j = 0; j < 8; ++j) p = fmaf(o[j], o[j], p);
        red[mloc * 16 + tx] = p;
    }
    __syncthreads();
    if (tid < 128) {
        float s = 0.f;
#pragma unroll
        for (int k = 0; k < 16; ++k) s += red[tid * 16 + k];
        atomicAdd(&cnorm[m0 + tid], s);    // 2 contributions/row, commutative
    }
}

// -------------------------------------------------------------------------
// Kernel 2: X -> xnorm + bf16 Xb (row-major; A-loads are once per wave).
// -------------------------------------------------------------------------
__global__ void convx_kernel(const float* __restrict__ X, float* __restrict__ xnorm,
                             unsigned short* __restrict__ Xb)
{
    const int wave = threadIdx.x >> 6;
    const int lane = threadIdx.x & 63;
    const int row  = blockIdx.x * 4 + wave;
    float4 v = *(const float4*)&X[(size_t)row * DIMD + lane * 4];
    ushort4 h = {f2bf(v.x), f2bf(v.y), f2bf(v.z), f2bf(v.w)};
    *(ushort4*)&Xb[(size_t)row * DIMD + lane * 4] = h;
    float s = v.x * v.x + v.y * v.y + v.z * v.z + v.w * v.w;
#pragma unroll
    for (int off = 1; off < 64; off <<= 1) s += __shfl_xor(s, off);
    if (lane == 0) xnorm[row] = s;
}

// -------------------------------------------------------------------------
// Kernel 3a: PASS 1 — pure min-GEMM, 32 TOKENS/WAVE (round-7 experiment:
// A-frags 64 VGPRs, est. total ~165 regs -> should clear the 170-reg
// 3-waves/SIMD occupancy step naturally; launch_bounds NOT forced).
// One 16-lane reduce + block combine, one global atomicMin per token.
// -------------------------------------------------------------------------
__global__ __launch_bounds__(256, 2)
void dist_min_kernel(const unsigned short* __restrict__ Xb,
                     const unsigned short* __restrict__ Cb2,
                     const float* __restrict__ cnorm,
                     unsigned* __restrict__ minkey)
{
    __shared__ float wmin[4][32];

    const int tid  = threadIdx.x;
    const int lane = tid & 63;
    const int wv   = tid >> 6;
    const int l15  = lane & 15;
    const int quad = lane >> 4;
    const int tok0 = blockIdx.x * 32;
    const int cbase = blockIdx.y * (NCODE / SPLITS_B) + wv * CODES_PER_WAVE;

    // A fragments: 32 tokens x 256 k, register-resident (64 regs)
    short8 a[2][8];
#pragma unroll
    for (int i = 0; i < 2; ++i) {
        const unsigned short* ap = Xb + (size_t)(tok0 + i * 16 + l15) * DIMD + quad * 8;
#pragma unroll
        for (int ks = 0; ks < 8; ++ks)
            a[i][ks] = *(const short8*)(ap + ks * 32);
    }

    float runv[8];
#pragma unroll
    for (int s = 0; s < 8; ++s) runv[s] = 3.4e38f;

    const unsigned short* bp0 = Cb2 + (size_t)cbase * DIMD + lane * 8;

    short8 breg[2][8];
    float  cnr[2];
#pragma unroll
    for (int ks = 0; ks < 8; ++ks) breg[0][ks] = *(const short8*)(bp0 + ks * 512);
    cnr[0] = cnorm[cbase + l15];

    auto group_body = [&](int g, short8 (&bc)[8], short8 (&bn)[8],
                          float cnc, float& cnn) {
        if (g + 1 < NGROUPS) {
            const unsigned short* bpn = bp0 + (size_t)(g + 1) * 4096;
#pragma unroll
            for (int ks = 0; ks < 8; ++ks) bn[ks] = *(const short8*)(bpn + ks * 512);
            cnn = cnorm[cbase + (g + 1) * 16 + l15];
        }

        floatx4 acc[2];
#pragma unroll
        for (int i = 0; i < 2; ++i) acc[i] = (floatx4){0.f, 0.f, 0.f, 0.f};
#pragma unroll
        for (int ks = 0; ks < 8; ++ks)
#pragma unroll
            for (int i = 0; i < 2; ++i)
                acc[i] = __builtin_amdgcn_mfma_f32_16x16x32_bf16(a[i][ks], bc[ks], acc[i], 0, 0, 0);

#pragma unroll
        for (int i = 0; i < 2; ++i)
#pragma unroll
            for (int r = 0; r < 4; ++r)
                runv[i * 4 + r] = fminf(runv[i * 4 + r], fmaf(-2.f, acc[i][r], cnc));
    };

    for (int gg = 0; gg < NGROUPS; gg += 2) {
        group_body(gg,     breg[0], breg[1], cnr[0], cnr[1]);
        group_body(gg + 1, breg[1], breg[0], cnr[1], cnr[0]);
    }

    // end-of-kernel reduce: min over this wave's 16 code-lanes
#pragma unroll
    for (int s = 0; s < 8; ++s) {
        float m = runv[s];
#pragma unroll
        for (int off = 1; off < 16; off <<= 1) m = fminf(m, __shfl_xor(m, off));
        runv[s] = m;
    }
    if (l15 == 0) {
#pragma unroll
        for (int i = 0; i < 2; ++i)
#pragma unroll
            for (int r = 0; r < 4; ++r)
                wmin[wv][i * 16 + quad * 4 + r] = runv[i * 4 + r];
    }
    __syncthreads();
    if (tid < 32) {
        const float bm = fminf(fminf(wmin[0][tid], wmin[1][tid]),
                               fminf(wmin[2][tid], wmin[3][tid]));
        atomicMin(&minkey[tok0 + tid], fkey(bm));
    }
}

// -------------------------------------------------------------------------
// Kernel 3b: PASS 2 — round-5 form (64 tokens/wave, single-chain acc,
// same-run CONTROL for the round-7 experiment). Recompute vs the FINAL
// global per-token threshold; rare hits staged in LDS; ONE device atomic
// per block.
// -------------------------------------------------------------------------
__global__ __launch_bounds__(256, 2)
void dist_emit_kernel(const unsigned short* __restrict__ Xb,
                      const unsigned short* __restrict__ Cb2,
                      const float* __restrict__ cnorm,
                      const unsigned* __restrict__ minkey,
                      unsigned* __restrict__ list, unsigned* __restrict__ count,
                      unsigned cap)
{
    __shared__ float tokthr[64];
    __shared__ unsigned ebuf[EBUF_CAP];
    __shared__ unsigned ecnt, gbase;

    const int tid  = threadIdx.x;
    const int lane = tid & 63;
    const int wv   = tid >> 6;
    const int l15  = lane & 15;
    const int quad = lane >> 4;
    const int tok0 = blockIdx.x * 64;
    const int cbase = blockIdx.y * (NCODE / SPLITS_B) + wv * CODES_PER_WAVE;

    if (tid == 0) ecnt = 0;
    if (tid < 64) tokthr[tid] = funkey(minkey[tok0 + tid]) + MARGIN;
    __syncthreads();

    short8 a[4][8];
#pragma unroll
    for (int i = 0; i < 4; ++i) {
        const unsigned short* ap = Xb + (size_t)(tok0 + i * 16 + l15) * DIMD + quad * 8;
#pragma unroll
        for (int ks = 0; ks < 8; ++ks)
            a[i][ks] = *(const short8*)(ap + ks * 32);
    }

    // fixed per-slot thresholds in registers (static indexing only)
    float thr[16];
#pragma unroll
    for (int i = 0; i < 4; ++i)
#pragma unroll
        for (int r = 0; r < 4; ++r)
            thr[i * 4 + r] = tokthr[i * 16 + quad * 4 + r];

    const unsigned short* bp0 = Cb2 + (size_t)cbase * DIMD + lane * 8;

    short8 breg[2][8];
    float  cnr[2];
#pragma unroll
    for (int ks = 0; ks < 8; ++ks) breg[0][ks] = *(const short8*)(bp0 + ks * 512);
    cnr[0] = cnorm[cbase + l15];

    auto group_body = [&](int g, short8 (&bc)[8], short8 (&bn)[8],
                          float cnc, float& cnn) {
        const int code0 = cbase + g * 16;
        if (g + 1 < NGROUPS) {
            const unsigned short* bpn = bp0 + (size_t)(g + 1) * 4096;
#pragma unroll
            for (int ks = 0; ks < 8; ++ks) bn[ks] = *(const short8*)(bpn + ks * 512);
            cnn = cnorm[code0 + 16 + l15];
        }

        floatx4 acc[4];
#pragma unroll
        for (int i = 0; i < 4; ++i) acc[i] = (floatx4){0.f, 0.f, 0.f, 0.f};
#pragma unroll
        for (int ks = 0; ks < 8; ++ks)
#pragma unroll
            for (int i = 0; i < 4; ++i)
                acc[i] = __builtin_amdgcn_mfma_f32_16x16x32_bf16(a[i][ks], bc[ks], acc[i], 0, 0, 0);

        unsigned mask = 0;
#pragma unroll
        for (int i = 0; i < 4; ++i)
#pragma unroll
            for (int r = 0; r < 4; ++r) {
                const float dd = fmaf(-2.f, acc[i][r], cnc);
                if (dd < thr[i * 4 + r]) mask |= (1u << (i * 4 + r));
            }

        if (__any(mask != 0)) {
            if (mask) {
                unsigned pos = atomicAdd(&ecnt, (unsigned)__popc(mask));
#pragma unroll
                for (int i = 0; i < 4; ++i)
#pragma unroll
                    for (int r = 0; r < 4; ++r) {
                        const int s = i * 4 + r;
                        if (mask & (1u << s)) {
                            const unsigned token = tok0 + i * 16 + quad * 4 + r;
                            const unsigned entry = (token << 13) | (unsigned)(code0 + l15);
                            if (pos < EBUF_CAP) ebuf[pos] = entry;
                            else { unsigned gp = atomicAdd(count, 1u); if (gp < cap) list[gp] = entry; }
                            ++pos;
                        }
                    }
            }
        }
    };

    for (int gg = 0; gg < NGROUPS; gg += 2) {
        group_body(gg,     breg[0], breg[1], cnr[0], cnr[1]);
        group_body(gg + 1, breg[1], breg[0], cnr[1], cnr[0]);
    }

    __syncthreads();
    const unsigned n = (ecnt < EBUF_CAP) ? ecnt : EBUF_CAP;
    if (tid == 0) gbase = atomicAdd(count, n);
    __syncthreads();
    const unsigned gb = gbase;
    for (unsigned i = tid; i < n; i += 256) {
        const unsigned p = gb + i;
        if (p < cap) list[p] = ebuf[i];
    }
}

// -------------------------------------------------------------------------
// Kernel 4: exact fp32 rescore. 16-lane groups, 4 candidates per wave.
// Packed (d_bits<<32 | code) atomicMin -> lowest-index tie-break.
// -------------------------------------------------------------------------
__global__ __launch_bounds__(256)
void rescore_kernel(const float* __restrict__ X, const float* __restrict__ C,
                    const float* __restrict__ xnorm, const float* __restrict__ cnorm,
                    const unsigned* __restrict__ list, const unsigned* __restrict__ count,
                    unsigned cap, unsigned long long* __restrict__ fin)
{
    const int lane = threadIdx.x & 63;
    const int g16  = lane & 15;
    const int sub  = lane >> 4;
    const int gid  = ((blockIdx.x * 256 + threadIdx.x) >> 6) * 4 + sub;
    const int ng   = ((gridDim.x * 256) >> 6) * 4;
    unsigned n = *count; if (n > cap) n = cap;

    for (unsigned c = gid; c < n; c += ng) {
        const unsigned e = list[c];
        const unsigned tok = e >> 13, code = e & 8191u;
        const float* xr = &X[(size_t)tok * DIMD];
        const float* cr = &C[(size_t)code * DIMD];
        float dot = 0.f;
#pragma unroll
        for (int r = 0; r < 4; ++r) {
            float4 x4 = *(const float4*)&xr[r * 64 + g16 * 4];
            float4 c4 = *(const float4*)&cr[r * 64 + g16 * 4];
            dot = fmaf(x4.x, c4.x, dot);
            dot = fmaf(x4.y, c4.y, dot);
            dot = fmaf(x4.z, c4.z, dot);
            dot = fmaf(x4.w, c4.w, dot);
        }
#pragma unroll
        for (int d = 1; d < 16; d <<= 1) dot += __shfl_xor(dot, d);
        if (g16 == 0) {
            const float dd = xnorm[tok] + cnorm[code] - 2.f * dot;
            const unsigned long long p =
                ((unsigned long long)__float_as_uint(dd) << 32) | code;
            atomicMin(&fin[tok], p);
        }
    }
}

// -------------------------------------------------------------------------
// Kernel 5: gather winner, straight-through output, loss. One atomic/block.
// -------------------------------------------------------------------------
__global__ __launch_bounds__(256)
void finalize_kernel(const float* __restrict__ X, const float* __restrict__ C,
                     const unsigned long long* __restrict__ fin,
                     float* __restrict__ out)
{
    __shared__ float part[4];
    const int lane = threadIdx.x & 63;
    const int wv   = threadIdx.x >> 6;
    const int t0   = blockIdx.x * 64;

    float local = 0.f;
    for (int it = 0; it < 16; ++it) {
        const int t = t0 + wv * 16 + it;
        const unsigned code = (unsigned)(fin[t] & 0xFFFFFFFFull);
        float4 c4 = *(const float4*)&C[(size_t)code * DIMD + lane * 4];
        float4 x4 = *(const float4*)&X[(size_t)t * DIMD + lane * 4];
        float4 w  = {c4.x - x4.x, c4.y - x4.y, c4.z - x4.z, c4.w - x4.w};
        local += w.x * w.x + w.y * w.y + w.z * w.z + w.w * w.w;
        float4 zq = {x4.x + w.x, x4.y + w.y, x4.z + w.z, x4.w + w.w};
        *(float4*)&out[(size_t)t * DIMD + lane * 4] = zq;
        if (lane == 0) out[NELEM + 1 + t] = (float)code;
    }
#pragma unroll
    for (int off = 1; off < 64; off <<= 1) local += __shfl_xor(local, off);
    if (lane == 0) part[wv] = local;
    __syncthreads();
    if (threadIdx.x == 0) {
        const float s = part[0] + part[1] + part[2] + part[3];
        atomicAdd(&out[NELEM], s * (1.25f / (float)NELEM));
    }
}

// -------------------------------------------------------------------------
extern "C" void kernel_launch(void* const* d_in, const int* in_sizes, int n_in,
                              void* d_out, int out_size, void* d_ws, size_t ws_size,
                              hipStream_t stream)
{
    const float* X = (const float*)d_in[0];
    const float* E = (const float*)d_in[1];
    const float* W = (const float*)d_in[2];
    const float* b = (const float*)d_in[3];
    float* out = (float*)d_out;

    char* w = (char*)d_ws;
    float* C            = (float*)w;           w += (size_t)NCODE * DIMD * 4;
    unsigned short* Xb  = (unsigned short*)w;  w += (size_t)NTOK * DIMD * 2;
    unsigned short* Cb2 = (unsigned short*)w;  w += (size_t)NCODE * DIMD * 2;
    float* xnorm        = (float*)w;           w += (size_t)NTOK * 4;
    // zero-group: cnorm + cnt adjacent -> one memset(0)
    float* cnorm        = (float*)w;           w += (size_t)NCODE * 4;
    unsigned* cnt       = (unsigned*)w;        w += 256;
    // 0xFF-group: fin + minkey adjacent -> one memset(0xFF)
    unsigned long long* fin = (unsigned long long*)w; w += (size_t)NTOK * 8;
    unsigned* minkey    = (unsigned*)w;        w += (size_t)NTOK * 4;
    unsigned* list      = (unsigned*)w;

    size_t used = (size_t)(w - (char*)d_ws);
    size_t avail = (ws_size > used) ? (ws_size - used) / 4 : 0;
    unsigned cap = (unsigned)((avail > 16777216u) ? 16777216u : avail);

    hipMemsetAsync(cnorm, 0, (size_t)NCODE * 4 + 256, stream);
    hipMemsetAsync(fin, 0xFF, (size_t)NTOK * 8 + (size_t)NTOK * 4, stream);
    hipMemsetAsync(out + NELEM, 0, 4, stream);

    project_kernel<<<dim3(NCODE / BM, DIMD / BK), 256, 0, stream>>>(E, W, b, C, Cb2, cnorm);
    convx_kernel<<<NTOK / 4, 256, 0, stream>>>(X, xnorm, Xb);
    dist_min_kernel<<<dim3(NTOK / 32, SPLITS_B), 256, 0, stream>>>(
        Xb, Cb2, cnorm, minkey);
    dist_emit_kernel<<<dim3(NTOK / 64, SPLITS_B), 256, 0, stream>>>(
        Xb, Cb2, cnorm, minkey, list, cnt, cap);
    rescore_kernel<<<1024, 256, 0, stream>>>(X, C, xnorm, cnorm, list, cnt, cap, fin);
    finalize_kernel<<<NTOK / 64, 256, 0, stream>>>(X, C, fin, out);
}

// Round 8
// 305.182 us; speedup vs baseline: 1.0161x; 1.0036x over previous
//
#include <hip/hip_runtime.h>

// Problem constants
#define DIMD   256
#define NTOK   16384
#define NCODE  8192
#define NELEM  (NTOK * DIMD)

// fp32 project-GEMM tiling
#define BM 128
#define BK 128
#define BD 32
#define PAD 4
#define LDS_STRIDE (BM + PAD)

// distance kernels — two-pass, 64 tokens/wave (round-7 lesson: 32-tok/wave
//   halves arithmetic intensity vs B and is NET SLOWER despite +occupancy).
// Round-1 lesson: never force launch_bounds min-waves up (spills).
// Round-2 lesson (rule #20): never runtime-index acc[] (LDS demotion).
// Round-4/5 lesson: device-scope same-address atomics in the hot loop
//   serialize the device; LDS staging + 1 global atomic/block only.
// Round-6 lesson: ~230 true regs/wave (incl A-frags+acc); +16 regs spills.
// Round-8 change: B staged via global_load_lds -> per-wave LDS, depth-2,
//   counted vmcnt(8) (never 0), barrier-free (per-wave LDS regions).
//   Kills the 64-reg breg dbuf; cnorm moved to LDS so the loop's only
//   VMEM is the counted stage. WAR on buffer reuse closed by lgkmcnt(0)
//   before each stage issue.
#define SPLITS_B 4                    // grid.y code splits
#define CODES_PER_WAVE (NCODE / SPLITS_B / 4)   // 512
#define NGROUPS (CODES_PER_WAVE / 16)           // 32
#define MARGIN 0.5f                   // > two-sided worst-case bf16 distance error
#define EBUF_CAP 1024                 // per-block emit staging (expected ~32 hits)

typedef float floatx4 __attribute__((ext_vector_type(4)));
typedef short short8  __attribute__((ext_vector_type(8)));
typedef unsigned int u32;

__device__ __forceinline__ unsigned short f2bf(float f) {
    unsigned u = __float_as_uint(f);
    unsigned r = (u + 0x7FFFu + ((u >> 16) & 1u)) >> 16;
    return (unsigned short)r;
}

// async 16B/lane global->LDS DMA: dest = lds + lane*16 (linear), src per-lane
__device__ __forceinline__ void gl_lds16(const void* g, void* l) {
    __builtin_amdgcn_global_load_lds(
        (const __attribute__((address_space(1))) u32*)g,
        (__attribute__((address_space(3))) u32*)l, 16, 0, 0);
}

// monotone float<->uint key (handles negative partial distances)
__device__ __forceinline__ unsigned fkey(float f) {
    unsigned u = __float_as_uint(f);
    return (u & 0x80000000u) ? ~u : (u | 0x80000000u);
}
__device__ __forceinline__ float funkey(unsigned k) {
    unsigned u = (k & 0x80000000u) ? (k & 0x7FFFFFFFu) : ~k;
    return __uint_as_float(u);
}

// fragment-major Cb index for element (row=code, col=k):
// block (row/16, col/32) of 512 elems; within: lane=(colsub/8)*16+(row%16), elem=col%8
__device__ __forceinline__ size_t cb2_idx(int row, int col) {
    return ((size_t)((row >> 4) * 8 + (col >> 5))) * 512
         + (size_t)((((col >> 3) & 3) * 16 + (row & 15)) * 8 + (col & 7));
}

// -------------------------------------------------------------------------
// Kernel 1: codebook projection C = E @ W^T + b (fp32) + fragment-major
// bf16 copy Cb2 + FUSED cnorm (block-local LDS reduce -> 2 commutative
// fp32 atomicAdds per row; exact for 2 partials).
// -------------------------------------------------------------------------
__global__ __launch_bounds__(256, 3)
void project_kernel(const float* __restrict__ E, const float* __restrict__ W,
                    const float* __restrict__ bias, float* __restrict__ C,
                    unsigned short* __restrict__ Cb2, float* __restrict__ cnorm)
{
    __shared__ float smem[2 * BD * LDS_STRIDE];
    float* As = smem;
    float* Bs = smem + BD * LDS_STRIDE;

    const int tid = threadIdx.x;
    const int tx  = tid & 15;
    const int ty  = tid >> 4;
    const int m0  = blockIdx.x * BM;
    const int j0  = blockIdx.y * BK;

    const int srow = tid >> 3;
    const int scol = (tid & 7) * 4;

    float acc[8][8];
#pragma unroll
    for (int i = 0; i < 8; ++i)
#pragma unroll
        for (int j = 0; j < 8; ++j) acc[i][j] = 0.f;

    for (int dc = 0; dc < DIMD / BD; ++dc) {
        const int d0 = dc * BD;
        __syncthreads();
#pragma unroll
        for (int rr = 0; rr < 4; ++rr) {
            const int r = srow + rr * 32;
            float4 av = *(const float4*)&E[(size_t)(m0 + r) * DIMD + d0 + scol];
            As[(scol + 0) * LDS_STRIDE + r] = av.x;
            As[(scol + 1) * LDS_STRIDE + r] = av.y;
            As[(scol + 2) * LDS_STRIDE + r] = av.z;
            As[(scol + 3) * LDS_STRIDE + r] = av.w;
            float4 bv = *(const float4*)&W[(size_t)(j0 + r) * DIMD + d0 + scol];
            Bs[(scol + 0) * LDS_STRIDE + r] = bv.x;
            Bs[(scol + 1) * LDS_STRIDE + r] = bv.y;
            Bs[(scol + 2) * LDS_STRIDE + r] = bv.z;
            Bs[(scol + 3) * LDS_STRIDE + r] = bv.w;
        }
        __syncthreads();
#pragma unroll 4
        for (int d = 0; d < BD; ++d) {
            float4 a0 = *(float4*)&As[d * LDS_STRIDE + ty * 4];
            float4 a1 = *(float4*)&As[d * LDS_STRIDE + 64 + ty * 4];
            float4 b0 = *(float4*)&Bs[d * LDS_STRIDE + tx * 4];
            float4 b1 = *(float4*)&Bs[d * LDS_STRIDE + 64 + tx * 4];
            float a[8] = {a0.x, a0.y, a0.z, a0.w, a1.x, a1.y, a1.z, a1.w};
            float b[8] = {b0.x, b0.y, b0.z, b0.w, b1.x, b1.y, b1.z, b1.w};
#pragma unroll
            for (int i = 0; i < 8; ++i)
#pragma unroll
                for (int j = 0; j < 8; ++j) acc[i][j] = fmaf(a[i], b[j], acc[i][j]);
        }
    }

    // epilogue: bias, stores, and per-row |c|^2 partials into LDS
    __syncthreads();                       // done reading As/Bs; reuse smem
    float* red = smem;                     // [128 rows][16 tx] partials

    float4 bja = *(const float4*)&bias[j0 + tx * 4];
    float4 bjb = *(const float4*)&bias[j0 + 64 + tx * 4];
#pragma unroll
    for (int i = 0; i < 8; ++i) {
        const int mloc = (i < 4) ? (ty * 4 + i) : (64 + ty * 4 + (i - 4));
        const int row  = m0 + mloc;
        const size_t rbase = (size_t)row * DIMD;
        float o[8] = {acc[i][0] + bja.x, acc[i][1] + bja.y, acc[i][2] + bja.z, acc[i][3] + bja.w,
                      acc[i][4] + bjb.x, acc[i][5] + bjb.y, acc[i][6] + bjb.z, acc[i][7] + bjb.w};
        *(float4*)&C[rbase + j0 + tx * 4]      = *(float4*)&o[0];
        *(float4*)&C[rbase + j0 + 64 + tx * 4] = *(float4*)&o[4];
        ushort4 h0 = {f2bf(o[0]), f2bf(o[1]), f2bf(o[2]), f2bf(o[3])};
        ushort4 h1 = {f2bf(o[4]), f2bf(o[5]), f2bf(o[6]), f2bf(o[7])};
        *(ushort4*)&Cb2[cb2_idx(row, j0 + tx * 4)]      = h0;
        *(ushort4*)&Cb2[cb2_idx(row, j0 + 64 + tx * 4)] = h1;
        float p = 0.f;
#pragma unroll
        for (int j = 0; j < 8; ++j) p = fmaf(o[j], o[j], p);
        red[mloc * 16 + tx] = p;
    }
    __syncthreads();
    if (tid < 128) {
        float s = 0.f;
#pragma unroll
        for (int k = 0; k < 16; ++k) s += red[tid * 16 + k];
        atomicAdd(&cnorm[m0 + tid], s);    // 2 contributions/row, commutative
    }
}

// -------------------------------------------------------------------------
// Kernel 2: X -> xnorm + bf16 Xb (row-major; A-loads are once per wave).
// -------------------------------------------------------------------------
__global__ void convx_kernel(const float* __restrict__ X, float* __restrict__ xnorm,
                             unsigned short* __restrict__ Xb)
{
    const int wave = threadIdx.x >> 6;
    const int lane = threadIdx.x & 63;
    const int row  = blockIdx.x * 4 + wave;
    float4 v = *(const float4*)&X[(size_t)row * DIMD + lane * 4];
    ushort4 h = {f2bf(v.x), f2bf(v.y), f2bf(v.z), f2bf(v.w)};
    *(ushort4*)&Xb[(size_t)row * DIMD + lane * 4] = h;
    float s = v.x * v.x + v.y * v.y + v.z * v.z + v.w * v.w;
#pragma unroll
    for (int off = 1; off < 64; off <<= 1) s += __shfl_xor(s, off);
    if (lane == 0) xnorm[row] = s;
}

// -------------------------------------------------------------------------
// Kernel 3a: PASS 1 — pure min-GEMM, 64 tok/wave, B via depth-2 async LDS
// pipeline (global_load_lds + counted vmcnt(8), barrier-free).
// -------------------------------------------------------------------------
__global__ __launch_bounds__(256, 2)
void dist_min_kernel(const unsigned short* __restrict__ Xb,
                     const unsigned short* __restrict__ Cb2,
                     const float* __restrict__ cnorm,
                     unsigned* __restrict__ minkey)
{
    __shared__ short Bls[4][2][4096];          // 64 KB: [wave][buf][8KB group]
    __shared__ float cnl[4][CODES_PER_WAVE];   // 8 KB cnorm slices
    __shared__ float wmin[4][64];

    const int tid  = threadIdx.x;
    const int lane = tid & 63;
    const int wv   = tid >> 6;
    const int l15  = lane & 15;
    const int quad = lane >> 4;
    const int tok0 = blockIdx.x * 64;
    const int cbase = blockIdx.y * (NCODE / SPLITS_B) + wv * CODES_PER_WAVE;

    // stage this wave's cnorm slice (512 floats = 2 KB) into LDS
    gl_lds16(cnorm + cbase + 0   + lane * 4, &cnl[wv][0]);
    gl_lds16(cnorm + cbase + 256 + lane * 4, &cnl[wv][256]);

    // B stage: group g = 8 KB contiguous in fragment-major Cb2
    const unsigned short* bsrc = Cb2 + (size_t)cbase * DIMD;
    auto STAGE = [&](int g) {
        const unsigned short* s = bsrc + (size_t)g * 4096 + lane * 8;
        short* d = &Bls[wv][g & 1][0];
#pragma unroll
        for (int j = 0; j < 8; ++j)
            gl_lds16(s + j * 512, d + j * 512);
    };
    STAGE(0);
    STAGE(1);

    // A fragments: 64 tokens x 256 k, register-resident (128 regs)
    short8 a[4][8];
#pragma unroll
    for (int i = 0; i < 4; ++i) {
        const unsigned short* ap = Xb + (size_t)(tok0 + i * 16 + l15) * DIMD + quad * 8;
#pragma unroll
        for (int ks = 0; ks < 8; ++ks)
            a[i][ks] = *(const short8*)(ap + ks * 32);
    }

    float runv[16];
#pragma unroll
    for (int s = 0; s < 16; ++s) runv[s] = 3.4e38f;

    for (int g = 0; g < NGROUPS; ++g) {
        // wait until group g's 8 DMA loads landed (8 newest = group g+1 stay in flight)
        asm volatile("s_waitcnt vmcnt(8)" ::: "memory");
        const short* bp = &Bls[wv][g & 1][lane * 8];
        short8 bc[8];
#pragma unroll
        for (int ks = 0; ks < 8; ++ks) bc[ks] = *(const short8*)(bp + ks * 512);
        const float cnc = cnl[wv][g * 16 + l15];
        // drain ds_reads BEFORE issuing the DMA that overwrites buf[g&1] (WAR)
        asm volatile("s_waitcnt lgkmcnt(0)" ::: "memory");
        __builtin_amdgcn_sched_barrier(0);
        if (g + 2 < NGROUPS) STAGE(g + 2);

        floatx4 acc[4];
#pragma unroll
        for (int i = 0; i < 4; ++i) acc[i] = (floatx4){0.f, 0.f, 0.f, 0.f};
#pragma unroll
        for (int ks = 0; ks < 8; ++ks)
#pragma unroll
            for (int i = 0; i < 4; ++i)
                acc[i] = __builtin_amdgcn_mfma_f32_16x16x32_bf16(a[i][ks], bc[ks], acc[i], 0, 0, 0);

#pragma unroll
        for (int i = 0; i < 4; ++i)
#pragma unroll
            for (int r = 0; r < 4; ++r)
                runv[i * 4 + r] = fminf(runv[i * 4 + r], fmaf(-2.f, acc[i][r], cnc));
    }

    // end-of-kernel reduce: min over this wave's 16 code-lanes
#pragma unroll
    for (int s = 0; s < 16; ++s) {
        float m = runv[s];
#pragma unroll
        for (int off = 1; off < 16; off <<= 1) m = fminf(m, __shfl_xor(m, off));
        runv[s] = m;
    }
    if (l15 == 0) {
#pragma unroll
        for (int i = 0; i < 4; ++i)
#pragma unroll
            for (int r = 0; r < 4; ++r)
                wmin[wv][i * 16 + quad * 4 + r] = runv[i * 4 + r];
    }
    __syncthreads();
    if (tid < 64) {
        const float bm = fminf(fminf(wmin[0][tid], wmin[1][tid]),
                               fminf(wmin[2][tid], wmin[3][tid]));
        atomicMin(&minkey[tok0 + tid], fkey(bm));
    }
}

// -------------------------------------------------------------------------
// Kernel 3b: PASS 2 — recompute vs FINAL global per-token threshold, same
// depth-2 async-LDS B pipeline. Rare hits staged in block LDS; ONE device
// atomic per block.
// -------------------------------------------------------------------------
__global__ __launch_bounds__(256, 2)
void dist_emit_kernel(const unsigned short* __restrict__ Xb,
                      const unsigned short* __restrict__ Cb2,
                      const float* __restrict__ cnorm,
                      const unsigned* __restrict__ minkey,
                      unsigned* __restrict__ list, unsigned* __restrict__ count,
                      unsigned cap)
{
    __shared__ short Bls[4][2][4096];          // 64 KB
    __shared__ float cnl[4][CODES_PER_WAVE];   // 8 KB
    __shared__ float tokthr[64];
    __shared__ unsigned ebuf[EBUF_CAP];        // 4 KB
    __shared__ unsigned ecnt, gbase;

    const int tid  = threadIdx.x;
    const int lane = tid & 63;
    const int wv   = tid >> 6;
    const int l15  = lane & 15;
    const int quad = lane >> 4;
    const int tok0 = blockIdx.x * 64;
    const int cbase = blockIdx.y * (NCODE / SPLITS_B) + wv * CODES_PER_WAVE;

    gl_lds16(cnorm + cbase + 0   + lane * 4, &cnl[wv][0]);
    gl_lds16(cnorm + cbase + 256 + lane * 4, &cnl[wv][256]);

    const unsigned short* bsrc = Cb2 + (size_t)cbase * DIMD;
    auto STAGE = [&](int g) {
        const unsigned short* s = bsrc + (size_t)g * 4096 + lane * 8;
        short* d = &Bls[wv][g & 1][0];
#pragma unroll
        for (int j = 0; j < 8; ++j)
            gl_lds16(s + j * 512, d + j * 512);
    };
    STAGE(0);
    STAGE(1);

    if (tid == 0) ecnt = 0;
    if (tid < 64) tokthr[tid] = funkey(minkey[tok0 + tid]) + MARGIN;
    __syncthreads();

    short8 a[4][8];
#pragma unroll
    for (int i = 0; i < 4; ++i) {
        const unsigned short* ap = Xb + (size_t)(tok0 + i * 16 + l15) * DIMD + quad * 8;
#pragma unroll
        for (int ks = 0; ks < 8; ++ks)
            a[i][ks] = *(const short8*)(ap + ks * 32);
    }

    // fixed per-slot thresholds in registers (static indexing only)
    float thr[16];
#pragma unroll
    for (int i = 0; i < 4; ++i)
#pragma unroll
        for (int r = 0; r < 4; ++r)
            thr[i * 4 + r] = tokthr[i * 16 + quad * 4 + r];

    for (int g = 0; g < NGROUPS; ++g) {
        const int code0 = cbase + g * 16;
        asm volatile("s_waitcnt vmcnt(8)" ::: "memory");
        const short* bp = &Bls[wv][g & 1][lane * 8];
        short8 bc[8];
#pragma unroll
        for (int ks = 0; ks < 8; ++ks) bc[ks] = *(const short8*)(bp + ks * 512);
        const float cnc = cnl[wv][g * 16 + l15];
        asm volatile("s_waitcnt lgkmcnt(0)" ::: "memory");
        __builtin_amdgcn_sched_barrier(0);
        if (g + 2 < NGROUPS) STAGE(g + 2);

        floatx4 acc[4];
#pragma unroll
        for (int i = 0; i < 4; ++i) acc[i] = (floatx4){0.f, 0.f, 0.f, 0.f};
#pragma unroll
        for (int ks = 0; ks < 8; ++ks)
#pragma unroll
            for (int i = 0; i < 4; ++i)
                acc[i] = __builtin_amdgcn_mfma_f32_16x16x32_bf16(a[i][ks], bc[ks], acc[i], 0, 0, 0);

        unsigned mask = 0;
#pragma unroll
        for (int i = 0; i < 4; ++i)
#pragma unroll
            for (int r = 0; r < 4; ++r) {
                const float dd = fmaf(-2.f, acc[i][r], cnc);
                if (dd < thr[i * 4 + r]) mask |= (1u << (i * 4 + r));
            }

        if (__any(mask != 0)) {
            if (mask) {
                unsigned pos = atomicAdd(&ecnt, (unsigned)__popc(mask));
#pragma unroll
                for (int i = 0; i < 4; ++i)
#pragma unroll
                    for (int r = 0; r < 4; ++r) {
                        const int s = i * 4 + r;
                        if (mask & (1u << s)) {
                            const unsigned token = tok0 + i * 16 + quad * 4 + r;
                            const unsigned entry = (token << 13) | (unsigned)(code0 + l15);
                            if (pos < EBUF_CAP) ebuf[pos] = entry;
                            else { unsigned gp = atomicAdd(count, 1u); if (gp < cap) list[gp] = entry; }
                            ++pos;
                        }
                    }
            }
        }
    }

    __syncthreads();
    const unsigned n = (ecnt < EBUF_CAP) ? ecnt : EBUF_CAP;
    if (tid == 0) gbase = atomicAdd(count, n);
    __syncthreads();
    const unsigned gb = gbase;
    for (unsigned i = tid; i < n; i += 256) {
        const unsigned p = gb + i;
        if (p < cap) list[p] = ebuf[i];
    }
}

// -------------------------------------------------------------------------
// Kernel 4: exact fp32 rescore. 16-lane groups, 4 candidates per wave.
// Packed (d_bits<<32 | code) atomicMin -> lowest-index tie-break.
// -------------------------------------------------------------------------
__global__ __launch_bounds__(256)
void rescore_kernel(const float* __restrict__ X, const float* __restrict__ C,
                    const float* __restrict__ xnorm, const float* __restrict__ cnorm,
                    const unsigned* __restrict__ list, const unsigned* __restrict__ count,
                    unsigned cap, unsigned long long* __restrict__ fin)
{
    const int lane = threadIdx.x & 63;
    const int g16  = lane & 15;
    const int sub  = lane >> 4;
    const int gid  = ((blockIdx.x * 256 + threadIdx.x) >> 6) * 4 + sub;
    const int ng   = ((gridDim.x * 256) >> 6) * 4;
    unsigned n = *count; if (n > cap) n = cap;

    for (unsigned c = gid; c < n; c += ng) {
        const unsigned e = list[c];
        const unsigned tok = e >> 13, code = e & 8191u;
        const float* xr = &X[(size_t)tok * DIMD];
        const float* cr = &C[(size_t)code * DIMD];
        float dot = 0.f;
#pragma unroll
        for (int r = 0; r < 4; ++r) {
            float4 x4 = *(const float4*)&xr[r * 64 + g16 * 4];
            float4 c4 = *(const float4*)&cr[r * 64 + g16 * 4];
            dot = fmaf(x4.x, c4.x, dot);
            dot = fmaf(x4.y, c4.y, dot);
            dot = fmaf(x4.z, c4.z, dot);
            dot = fmaf(x4.w, c4.w, dot);
        }
#pragma unroll
        for (int d = 1; d < 16; d <<= 1) dot += __shfl_xor(dot, d);
        if (g16 == 0) {
            const float dd = xnorm[tok] + cnorm[code] - 2.f * dot;
            const unsigned long long p =
                ((unsigned long long)__float_as_uint(dd) << 32) | code;
            atomicMin(&fin[tok], p);
        }
    }
}

// -------------------------------------------------------------------------
// Kernel 5: gather winner, straight-through output, loss. One atomic/block.
// -------------------------------------------------------------------------
__global__ __launch_bounds__(256)
void finalize_kernel(const float* __restrict__ X, const float* __restrict__ C,
                     const unsigned long long* __restrict__ fin,
                     float* __restrict__ out)
{
    __shared__ float part[4];
    const int lane = threadIdx.x & 63;
    const int wv   = threadIdx.x >> 6;
    const int t0   = blockIdx.x * 64;

    float local = 0.f;
    for (int it = 0; it < 16; ++it) {
        const int t = t0 + wv * 16 + it;
        const unsigned code = (unsigned)(fin[t] & 0xFFFFFFFFull);
        float4 c4 = *(const float4*)&C[(size_t)code * DIMD + lane * 4];
        float4 x4 = *(const float4*)&X[(size_t)t * DIMD + lane * 4];
        float4 w  = {c4.x - x4.x, c4.y - x4.y, c4.z - x4.z, c4.w - x4.w};
        local += w.x * w.x + w.y * w.y + w.z * w.z + w.w * w.w;
        float4 zq = {x4.x + w.x, x4.y + w.y, x4.z + w.z, x4.w + w.w};
        *(float4*)&out[(size_t)t * DIMD + lane * 4] = zq;
        if (lane == 0) out[NELEM + 1 + t] = (float)code;
    }
#pragma unroll
    for (int off = 1; off < 64; off <<= 1) local += __shfl_xor(local, off);
    if (lane == 0) part[wv] = local;
    __syncthreads();
    if (threadIdx.x == 0) {
        const float s = part[0] + part[1] + part[2] + part[3];
        atomicAdd(&out[NELEM], s * (1.25f / (float)NELEM));
    }
}

// -------------------------------------------------------------------------
extern "C" void kernel_launch(void* const* d_in, const int* in_sizes, int n_in,
                              void* d_out, int out_size, void* d_ws, size_t ws_size,
                              hipStream_t stream)
{
    const float* X = (const float*)d_in[0];
    const float* E = (const float*)d_in[1];
    const float* W = (const float*)d_in[2];
    const float* b = (const float*)d_in[3];
    float* out = (float*)d_out;

    char* w = (char*)d_ws;
    float* C            = (float*)w;           w += (size_t)NCODE * DIMD * 4;
    unsigned short* Xb  = (unsigned short*)w;  w += (size_t)NTOK * DIMD * 2;
    unsigned short* Cb2 = (unsigned short*)w;  w += (size_t)NCODE * DIMD * 2;
    float* xnorm        = (float*)w;           w += (size_t)NTOK * 4;
    // zero-group: cnorm + cnt adjacent -> one memset(0)
    float* cnorm        = (float*)w;           w += (size_t)NCODE * 4;
    unsigned* cnt       = (unsigned*)w;        w += 256;
    // 0xFF-group: fin + minkey adjacent -> one memset(0xFF)
    unsigned long long* fin = (unsigned long long*)w; w += (size_t)NTOK * 8;
    unsigned* minkey    = (unsigned*)w;        w += (size_t)NTOK * 4;
    unsigned* list      = (unsigned*)w;

    size_t used = (size_t)(w - (char*)d_ws);
    size_t avail = (ws_size > used) ? (ws_size - used) / 4 : 0;
    unsigned cap = (unsigned)((avail > 16777216u) ? 16777216u : avail);

    hipMemsetAsync(cnorm, 0, (size_t)NCODE * 4 + 256, stream);
    hipMemsetAsync(fin, 0xFF, (size_t)NTOK * 8 + (size_t)NTOK * 4, stream);
    hipMemsetAsync(out + NELEM, 0, 4, stream);

    project_kernel<<<dim3(NCODE / BM, DIMD / BK), 256, 0, stream>>>(E, W, b, C, Cb2, cnorm);
    convx_kernel<<<NTOK / 4, 256, 0, stream>>>(X, xnorm, Xb);
    dist_min_kernel<<<dim3(NTOK / 64, SPLITS_B), 256, 0, stream>>>(
        Xb, Cb2, cnorm, minkey);
    dist_emit_kernel<<<dim3(NTOK / 64, SPLITS_B), 256, 0, stream>>>(
        Xb, Cb2, cnorm, minkey, list, cnt, cap);
    rescore_kernel<<<1024, 256, 0, stream>>>(X, C, xnorm, cnorm, list, cnt, cap, fin);
    finalize_kernel<<<NTOK / 64, 256, 0, stream>>>(X, C, fin, out);
}

// Round 9
// 278.206 us; speedup vs baseline: 1.1146x; 1.0970x over previous
//
#include <hip/hip_runtime.h>

// Problem constants
#define DIMD   256
#define NTOK   16384
#define NCODE  8192
#define NELEM  (NTOK * DIMD)

// fp32 project-GEMM tiling
#define BM 128
#define BK 128
#define BD 32
#define PAD 4
#define LDS_STRIDE (BM + PAD)

// distance kernels — two-pass, 64 tokens/wave, register B-dbuf (round-5
// form; LOCKED — beaten alternatives: forced occupancy (R1 spills), fused
// emission (R0/2/3), device atomics in loop (R4: 425us), acc-split ILP
// (R6 spills), 32-tok/wave (R7: halves intensity), async global_load_lds
// staging (R8: +17us from LDS round-trip + lgkmcnt serialization).
// Round-9 change: dispatch diet 9->5. project+convx fused (block-range
// split), all memsets eliminated (inits folded into convx blocks; cnorm
// atomicAdd -> two plain partial arrays cnormA/cnormB).
#define SPLITS_B 4                    // grid.y code splits
#define CODES_PER_WAVE (NCODE / SPLITS_B / 4)   // 512
#define NGROUPS (CODES_PER_WAVE / 16)           // 32
#define MARGIN 0.5f                   // > two-sided worst-case bf16 distance error
#define EBUF_CAP 1024                 // per-block emit staging (expected ~32 hits)

#define PROJ_BLOCKS ((NCODE / BM) * (DIMD / BK))   // 128
#define CONV_BLOCKS (NTOK / 4)                     // 4096

typedef float floatx4 __attribute__((ext_vector_type(4)));
typedef short short8  __attribute__((ext_vector_type(8)));

__device__ __forceinline__ unsigned short f2bf(float f) {
    unsigned u = __float_as_uint(f);
    unsigned r = (u + 0x7FFFu + ((u >> 16) & 1u)) >> 16;
    return (unsigned short)r;
}

// monotone float<->uint key (handles negative partial distances)
__device__ __forceinline__ unsigned fkey(float f) {
    unsigned u = __float_as_uint(f);
    return (u & 0x80000000u) ? ~u : (u | 0x80000000u);
}
__device__ __forceinline__ float funkey(unsigned k) {
    unsigned u = (k & 0x80000000u) ? (k & 0x7FFFFFFFu) : ~k;
    return __uint_as_float(u);
}

// fragment-major Cb index for element (row=code, col=k):
// block (row/16, col/32) of 512 elems; within: lane=(colsub/8)*16+(row%16), elem=col%8
__device__ __forceinline__ size_t cb2_idx(int row, int col) {
    return ((size_t)((row >> 4) * 8 + (col >> 5))) * 512
         + (size_t)((((col >> 3) & 3) * 16 + (row & 15)) * 8 + (col & 7));
}

// -------------------------------------------------------------------------
// Kernel 1 (fused prep): blocks [0,128) = codebook projection
// C = E @ W^T + b (fp32) + fragment-major bf16 Cb2 + per-row |c|^2 partial
// (plain store to cnormA/cnormB — one array per j0 half, no init needed).
// Blocks [128, 128+4096) = X -> xnorm + bf16 Xb, plus ALL buffer inits
// (fin/minkey per token; cnt/out[NELEM] by the first convx block).
// Stream order guarantees every consumer kernel sees completed inits.
// -------------------------------------------------------------------------
__global__ __launch_bounds__(256, 3)
void prep_kernel(const float* __restrict__ E, const float* __restrict__ W,
                 const float* __restrict__ bias, float* __restrict__ C,
                 unsigned short* __restrict__ Cb2,
                 float* __restrict__ cnormA, float* __restrict__ cnormB,
                 const float* __restrict__ X, float* __restrict__ xnorm,
                 unsigned short* __restrict__ Xb,
                 unsigned long long* __restrict__ fin,
                 unsigned* __restrict__ minkey,
                 unsigned* __restrict__ cnt, float* __restrict__ out)
{
    __shared__ float smem[2 * BD * LDS_STRIDE];

    const int bid = blockIdx.x;
    const int tid = threadIdx.x;

    if (bid >= PROJ_BLOCKS) {
        // ---- convx part + inits ----
        const int row0 = (bid - PROJ_BLOCKS) * 4;
        const int wave = tid >> 6;
        const int lane = tid & 63;
        const int row  = row0 + wave;
        float4 v = *(const float4*)&X[(size_t)row * DIMD + lane * 4];
        ushort4 h = {f2bf(v.x), f2bf(v.y), f2bf(v.z), f2bf(v.w)};
        *(ushort4*)&Xb[(size_t)row * DIMD + lane * 4] = h;
        float s = v.x * v.x + v.y * v.y + v.z * v.z + v.w * v.w;
#pragma unroll
        for (int off = 1; off < 64; off <<= 1) s += __shfl_xor(s, off);
        if (lane == 0) xnorm[row] = s;
        if (tid < 4) {
            fin[row0 + tid]    = ~0ull;
            minkey[row0 + tid] = ~0u;
        }
        if (bid == PROJ_BLOCKS && tid == 0) { *cnt = 0; out[NELEM] = 0.f; }
        return;
    }

    // ---- project part ----
    float* As = smem;
    float* Bs = smem + BD * LDS_STRIDE;

    const int tx  = tid & 15;
    const int ty  = tid >> 4;
    const int m0  = (bid & 63) * BM;
    const int j0  = (bid >> 6) * BK;

    const int srow = tid >> 3;
    const int scol = (tid & 7) * 4;

    float acc[8][8];
#pragma unroll
    for (int i = 0; i < 8; ++i)
#pragma unroll
        for (int j = 0; j < 8; ++j) acc[i][j] = 0.f;

    for (int dc = 0; dc < DIMD / BD; ++dc) {
        const int d0 = dc * BD;
        __syncthreads();
#pragma unroll
        for (int rr = 0; rr < 4; ++rr) {
            const int r = srow + rr * 32;
            float4 av = *(const float4*)&E[(size_t)(m0 + r) * DIMD + d0 + scol];
            As[(scol + 0) * LDS_STRIDE + r] = av.x;
            As[(scol + 1) * LDS_STRIDE + r] = av.y;
            As[(scol + 2) * LDS_STRIDE + r] = av.z;
            As[(scol + 3) * LDS_STRIDE + r] = av.w;
            float4 bv = *(const float4*)&W[(size_t)(j0 + r) * DIMD + d0 + scol];
            Bs[(scol + 0) * LDS_STRIDE + r] = bv.x;
            Bs[(scol + 1) * LDS_STRIDE + r] = bv.y;
            Bs[(scol + 2) * LDS_STRIDE + r] = bv.z;
            Bs[(scol + 3) * LDS_STRIDE + r] = bv.w;
        }
        __syncthreads();
#pragma unroll 4
        for (int d = 0; d < BD; ++d) {
            float4 a0 = *(float4*)&As[d * LDS_STRIDE + ty * 4];
            float4 a1 = *(float4*)&As[d * LDS_STRIDE + 64 + ty * 4];
            float4 b0 = *(float4*)&Bs[d * LDS_STRIDE + tx * 4];
            float4 b1 = *(float4*)&Bs[d * LDS_STRIDE + 64 + tx * 4];
            float a[8] = {a0.x, a0.y, a0.z, a0.w, a1.x, a1.y, a1.z, a1.w};
            float b[8] = {b0.x, b0.y, b0.z, b0.w, b1.x, b1.y, b1.z, b1.w};
#pragma unroll
            for (int i = 0; i < 8; ++i)
#pragma unroll
                for (int j = 0; j < 8; ++j) acc[i][j] = fmaf(a[i], b[j], acc[i][j]);
        }
    }

    // epilogue: bias, stores, per-row |c|^2 partial via LDS reduce
    __syncthreads();                       // done reading As/Bs; reuse smem
    float* red = smem;                     // [128 rows][16 tx]

    float4 bja = *(const float4*)&bias[j0 + tx * 4];
    float4 bjb = *(const float4*)&bias[j0 + 64 + tx * 4];
#pragma unroll
    for (int i = 0; i < 8; ++i) {
        const int mloc = (i < 4) ? (ty * 4 + i) : (64 + ty * 4 + (i - 4));
        const int row  = m0 + mloc;
        const size_t rbase = (size_t)row * DIMD;
        float o[8] = {acc[i][0] + bja.x, acc[i][1] + bja.y, acc[i][2] + bja.z, acc[i][3] + bja.w,
                      acc[i][4] + bjb.x, acc[i][5] + bjb.y, acc[i][6] + bjb.z, acc[i][7] + bjb.w};
        *(float4*)&C[rbase + j0 + tx * 4]      = *(float4*)&o[0];
        *(float4*)&C[rbase + j0 + 64 + tx * 4] = *(float4*)&o[4];
        ushort4 h0 = {f2bf(o[0]), f2bf(o[1]), f2bf(o[2]), f2bf(o[3])};
        ushort4 h1 = {f2bf(o[4]), f2bf(o[5]), f2bf(o[6]), f2bf(o[7])};
        *(ushort4*)&Cb2[cb2_idx(row, j0 + tx * 4)]      = h0;
        *(ushort4*)&Cb2[cb2_idx(row, j0 + 64 + tx * 4)] = h1;
        float p = 0.f;
#pragma unroll
        for (int j = 0; j < 8; ++j) p = fmaf(o[j], o[j], p);
        red[mloc * 16 + tx] = p;
    }
    __syncthreads();
    if (tid < 128) {
        float s = 0.f;
#pragma unroll
        for (int k = 0; k < 16; ++k) s += red[tid * 16 + k];
        float* dst = (j0 == 0) ? cnormA : cnormB;
        dst[m0 + tid] = s;                 // plain store, per-(block,row) unique
    }
}

// -------------------------------------------------------------------------
// Kernel 2a: PASS 1 — pure min-GEMM, 64 tok/wave, register B double-buffer
// (round-5 locked form). One 16-lane reduce + block combine at end, one
// global atomicMin per token (monotone key, distinct addresses).
// -------------------------------------------------------------------------
__global__ __launch_bounds__(256, 2)
void dist_min_kernel(const unsigned short* __restrict__ Xb,
                     const unsigned short* __restrict__ Cb2,
                     const float* __restrict__ cnormA,
                     const float* __restrict__ cnormB,
                     unsigned* __restrict__ minkey)
{
    __shared__ float wmin[4][64];

    const int tid  = threadIdx.x;
    const int lane = tid & 63;
    const int wv   = tid >> 6;
    const int l15  = lane & 15;
    const int quad = lane >> 4;
    const int tok0 = blockIdx.x * 64;
    const int cbase = blockIdx.y * (NCODE / SPLITS_B) + wv * CODES_PER_WAVE;

    // A fragments: 64 tokens x 256 k, register-resident (128 regs)
    short8 a[4][8];
#pragma unroll
    for (int i = 0; i < 4; ++i) {
        const unsigned short* ap = Xb + (size_t)(tok0 + i * 16 + l15) * DIMD + quad * 8;
#pragma unroll
        for (int ks = 0; ks < 8; ++ks)
            a[i][ks] = *(const short8*)(ap + ks * 32);
    }

    float runv[16];
#pragma unroll
    for (int s = 0; s < 16; ++s) runv[s] = 3.4e38f;

    const unsigned short* bp0 = Cb2 + (size_t)cbase * DIMD + lane * 8;

    short8 breg[2][8];
    float  cnr[2];
#pragma unroll
    for (int ks = 0; ks < 8; ++ks) breg[0][ks] = *(const short8*)(bp0 + ks * 512);
    cnr[0] = cnormA[cbase + l15] + cnormB[cbase + l15];

    auto group_body = [&](int g, short8 (&bc)[8], short8 (&bn)[8],
                          float cnc, float& cnn) {
        if (g + 1 < NGROUPS) {
            const unsigned short* bpn = bp0 + (size_t)(g + 1) * 4096;
#pragma unroll
            for (int ks = 0; ks < 8; ++ks) bn[ks] = *(const short8*)(bpn + ks * 512);
            const int cnx = cbase + (g + 1) * 16 + l15;
            cnn = cnormA[cnx] + cnormB[cnx];
        }

        floatx4 acc[4];
#pragma unroll
        for (int i = 0; i < 4; ++i) acc[i] = (floatx4){0.f, 0.f, 0.f, 0.f};
#pragma unroll
        for (int ks = 0; ks < 8; ++ks)
#pragma unroll
            for (int i = 0; i < 4; ++i)
                acc[i] = __builtin_amdgcn_mfma_f32_16x16x32_bf16(a[i][ks], bc[ks], acc[i], 0, 0, 0);

#pragma unroll
        for (int i = 0; i < 4; ++i)
#pragma unroll
            for (int r = 0; r < 4; ++r)
                runv[i * 4 + r] = fminf(runv[i * 4 + r], fmaf(-2.f, acc[i][r], cnc));
    };

    for (int gg = 0; gg < NGROUPS; gg += 2) {
        group_body(gg,     breg[0], breg[1], cnr[0], cnr[1]);
        group_body(gg + 1, breg[1], breg[0], cnr[1], cnr[0]);
    }

    // end-of-kernel reduce: min over this wave's 16 code-lanes
#pragma unroll
    for (int s = 0; s < 16; ++s) {
        float m = runv[s];
#pragma unroll
        for (int off = 1; off < 16; off <<= 1) m = fminf(m, __shfl_xor(m, off));
        runv[s] = m;
    }
    if (l15 == 0) {
#pragma unroll
        for (int i = 0; i < 4; ++i)
#pragma unroll
            for (int r = 0; r < 4; ++r)
                wmin[wv][i * 16 + quad * 4 + r] = runv[i * 4 + r];
    }
    __syncthreads();
    if (tid < 64) {
        const float bm = fminf(fminf(wmin[0][tid], wmin[1][tid]),
                               fminf(wmin[2][tid], wmin[3][tid]));
        atomicMin(&minkey[tok0 + tid], fkey(bm));
    }
}

// -------------------------------------------------------------------------
// Kernel 2b: PASS 2 — recompute vs FINAL global per-token threshold
// (round-5 locked form). Rare hits staged in block LDS (LDS atomicAdd
// only); ONE device-scope atomic per block appends to the global list.
// -------------------------------------------------------------------------
__global__ __launch_bounds__(256, 2)
void dist_emit_kernel(const unsigned short* __restrict__ Xb,
                      const unsigned short* __restrict__ Cb2,
                      const float* __restrict__ cnormA,
                      const float* __restrict__ cnormB,
                      const unsigned* __restrict__ minkey,
                      unsigned* __restrict__ list, unsigned* __restrict__ count,
                      unsigned cap)
{
    __shared__ float tokthr[64];
    __shared__ unsigned ebuf[EBUF_CAP];
    __shared__ unsigned ecnt, gbase;

    const int tid  = threadIdx.x;
    const int lane = tid & 63;
    const int wv   = tid >> 6;
    const int l15  = lane & 15;
    const int quad = lane >> 4;
    const int tok0 = blockIdx.x * 64;
    const int cbase = blockIdx.y * (NCODE / SPLITS_B) + wv * CODES_PER_WAVE;

    if (tid == 0) ecnt = 0;
    if (tid < 64) tokthr[tid] = funkey(minkey[tok0 + tid]) + MARGIN;
    __syncthreads();

    short8 a[4][8];
#pragma unroll
    for (int i = 0; i < 4; ++i) {
        const unsigned short* ap = Xb + (size_t)(tok0 + i * 16 + l15) * DIMD + quad * 8;
#pragma unroll
        for (int ks = 0; ks < 8; ++ks)
            a[i][ks] = *(const short8*)(ap + ks * 32);
    }

    // fixed per-slot thresholds in registers (static indexing only)
    float thr[16];
#pragma unroll
    for (int i = 0; i < 4; ++i)
#pragma unroll
        for (int r = 0; r < 4; ++r)
            thr[i * 4 + r] = tokthr[i * 16 + quad * 4 + r];

    const unsigned short* bp0 = Cb2 + (size_t)cbase * DIMD + lane * 8;

    short8 breg[2][8];
    float  cnr[2];
#pragma unroll
    for (int ks = 0; ks < 8; ++ks) breg[0][ks] = *(const short8*)(bp0 + ks * 512);
    cnr[0] = cnormA[cbase + l15] + cnormB[cbase + l15];

    auto group_body = [&](int g, short8 (&bc)[8], short8 (&bn)[8],
                          float cnc, float& cnn) {
        const int code0 = cbase + g * 16;
        if (g + 1 < NGROUPS) {
            const unsigned short* bpn = bp0 + (size_t)(g + 1) * 4096;
#pragma unroll
            for (int ks = 0; ks < 8; ++ks) bn[ks] = *(const short8*)(bpn + ks * 512);
            const int cnx = code0 + 16 + l15;
            cnn = cnormA[cnx] + cnormB[cnx];
        }

        floatx4 acc[4];
#pragma unroll
        for (int i = 0; i < 4; ++i) acc[i] = (floatx4){0.f, 0.f, 0.f, 0.f};
#pragma unroll
        for (int ks = 0; ks < 8; ++ks)
#pragma unroll
            for (int i = 0; i < 4; ++i)
                acc[i] = __builtin_amdgcn_mfma_f32_16x16x32_bf16(a[i][ks], bc[ks], acc[i], 0, 0, 0);

        unsigned mask = 0;
#pragma unroll
        for (int i = 0; i < 4; ++i)
#pragma unroll
            for (int r = 0; r < 4; ++r) {
                const float dd = fmaf(-2.f, acc[i][r], cnc);
                if (dd < thr[i * 4 + r]) mask |= (1u << (i * 4 + r));
            }

        if (__any(mask != 0)) {
            if (mask) {
                unsigned pos = atomicAdd(&ecnt, (unsigned)__popc(mask));
#pragma unroll
                for (int i = 0; i < 4; ++i)
#pragma unroll
                    for (int r = 0; r < 4; ++r) {
                        const int s = i * 4 + r;
                        if (mask & (1u << s)) {
                            const unsigned token = tok0 + i * 16 + quad * 4 + r;
                            const unsigned entry = (token << 13) | (unsigned)(code0 + l15);
                            if (pos < EBUF_CAP) ebuf[pos] = entry;
                            else { unsigned gp = atomicAdd(count, 1u); if (gp < cap) list[gp] = entry; }
                            ++pos;
                        }
                    }
            }
        }
    };

    for (int gg = 0; gg < NGROUPS; gg += 2) {
        group_body(gg,     breg[0], breg[1], cnr[0], cnr[1]);
        group_body(gg + 1, breg[1], breg[0], cnr[1], cnr[0]);
    }

    __syncthreads();
    const unsigned n = (ecnt < EBUF_CAP) ? ecnt : EBUF_CAP;
    if (tid == 0) gbase = atomicAdd(count, n);
    __syncthreads();
    const unsigned gb = gbase;
    for (unsigned i = tid; i < n; i += 256) {
        const unsigned p = gb + i;
        if (p < cap) list[p] = ebuf[i];
    }
}

// -------------------------------------------------------------------------
// Kernel 3: exact fp32 rescore. 16-lane groups, 4 candidates per wave.
// Packed (d_bits<<32 | code) atomicMin -> lowest-index tie-break.
// -------------------------------------------------------------------------
__global__ __launch_bounds__(256)
void rescore_kernel(const float* __restrict__ X, const float* __restrict__ C,
                    const float* __restrict__ xnorm,
                    const float* __restrict__ cnormA,
                    const float* __restrict__ cnormB,
                    const unsigned* __restrict__ list, const unsigned* __restrict__ count,
                    unsigned cap, unsigned long long* __restrict__ fin)
{
    const int lane = threadIdx.x & 63;
    const int g16  = lane & 15;
    const int sub  = lane >> 4;
    const int gid  = ((blockIdx.x * 256 + threadIdx.x) >> 6) * 4 + sub;
    const int ng   = ((gridDim.x * 256) >> 6) * 4;
    unsigned n = *count; if (n > cap) n = cap;

    for (unsigned c = gid; c < n; c += ng) {
        const unsigned e = list[c];
        const unsigned tok = e >> 13, code = e & 8191u;
        const float* xr = &X[(size_t)tok * DIMD];
        const float* cr = &C[(size_t)code * DIMD];
        float dot = 0.f;
#pragma unroll
        for (int r = 0; r < 4; ++r) {
            float4 x4 = *(const float4*)&xr[r * 64 + g16 * 4];
            float4 c4 = *(const float4*)&cr[r * 64 + g16 * 4];
            dot = fmaf(x4.x, c4.x, dot);
            dot = fmaf(x4.y, c4.y, dot);
            dot = fmaf(x4.z, c4.z, dot);
            dot = fmaf(x4.w, c4.w, dot);
        }
#pragma unroll
        for (int d = 1; d < 16; d <<= 1) dot += __shfl_xor(dot, d);
        if (g16 == 0) {
            const float dd = xnorm[tok] + (cnormA[code] + cnormB[code]) - 2.f * dot;
            const unsigned long long p =
                ((unsigned long long)__float_as_uint(dd) << 32) | code;
            atomicMin(&fin[tok], p);
        }
    }
}

// -------------------------------------------------------------------------
// Kernel 4: gather winner, straight-through output, loss. One atomic/block.
// -------------------------------------------------------------------------
__global__ __launch_bounds__(256)
void finalize_kernel(const float* __restrict__ X, const float* __restrict__ C,
                     const unsigned long long* __restrict__ fin,
                     float* __restrict__ out)
{
    __shared__ float part[4];
    const int lane = threadIdx.x & 63;
    const int wv   = threadIdx.x >> 6;
    const int t0   = blockIdx.x * 64;

    float local = 0.f;
    for (int it = 0; it < 16; ++it) {
        const int t = t0 + wv * 16 + it;
        const unsigned code = (unsigned)(fin[t] & 0xFFFFFFFFull);
        float4 c4 = *(const float4*)&C[(size_t)code * DIMD + lane * 4];
        float4 x4 = *(const float4*)&X[(size_t)t * DIMD + lane * 4];
        float4 w  = {c4.x - x4.x, c4.y - x4.y, c4.z - x4.z, c4.w - x4.w};
        local += w.x * w.x + w.y * w.y + w.z * w.z + w.w * w.w;
        float4 zq = {x4.x + w.x, x4.y + w.y, x4.z + w.z, x4.w + w.w};
        *(float4*)&out[(size_t)t * DIMD + lane * 4] = zq;
        if (lane == 0) out[NELEM + 1 + t] = (float)code;
    }
#pragma unroll
    for (int off = 1; off < 64; off <<= 1) local += __shfl_xor(local, off);
    if (lane == 0) part[wv] = local;
    __syncthreads();
    if (threadIdx.x == 0) {
        const float s = part[0] + part[1] + part[2] + part[3];
        atomicAdd(&out[NELEM], s * (1.25f / (float)NELEM));
    }
}

// -------------------------------------------------------------------------
extern "C" void kernel_launch(void* const* d_in, const int* in_sizes, int n_in,
                              void* d_out, int out_size, void* d_ws, size_t ws_size,
                              hipStream_t stream)
{
    const float* X = (const float*)d_in[0];
    const float* E = (const float*)d_in[1];
    const float* W = (const float*)d_in[2];
    const float* b = (const float*)d_in[3];
    float* out = (float*)d_out;

    char* w = (char*)d_ws;
    float* C            = (float*)w;           w += (size_t)NCODE * DIMD * 4;
    unsigned short* Xb  = (unsigned short*)w;  w += (size_t)NTOK * DIMD * 2;
    unsigned short* Cb2 = (unsigned short*)w;  w += (size_t)NCODE * DIMD * 2;
    float* xnorm        = (float*)w;           w += (size_t)NTOK * 4;
    float* cnormA       = (float*)w;           w += (size_t)NCODE * 4;
    float* cnormB       = (float*)w;           w += (size_t)NCODE * 4;
    unsigned* cnt       = (unsigned*)w;        w += 256;
    unsigned long long* fin = (unsigned long long*)w; w += (size_t)NTOK * 8;
    unsigned* minkey    = (unsigned*)w;        w += (size_t)NTOK * 4;
    unsigned* list      = (unsigned*)w;

    size_t used = (size_t)(w - (char*)d_ws);
    size_t avail = (ws_size > used) ? (ws_size - used) / 4 : 0;
    unsigned cap = (unsigned)((avail > 16777216u) ? 16777216u : avail);

    // 5 dispatches, zero memsets: all inits live inside prep_kernel.
    prep_kernel<<<PROJ_BLOCKS + CONV_BLOCKS, 256, 0, stream>>>(
        E, W, b, C, Cb2, cnormA, cnormB, X, xnorm, Xb, fin, minkey, cnt, out);
    dist_min_kernel<<<dim3(NTOK / 64, SPLITS_B), 256, 0, stream>>>(
        Xb, Cb2, cnormA, cnormB, minkey);
    dist_emit_kernel<<<dim3(NTOK / 64, SPLITS_B), 256, 0, stream>>>(
        Xb, Cb2, cnormA, cnormB, minkey, list, cnt, cap);
    rescore_kernel<<<1024, 256, 0, stream>>>(X, C, xnorm, cnormA, cnormB, list, cnt, cap, fin);
    finalize_kernel<<<NTOK / 64, 256, 0, stream>>>(X, C, fin, out);
}

// Round 10
// 273.690 us; speedup vs baseline: 1.1330x; 1.0165x over previous
//
#include <hip/hip_runtime.h>

// Problem constants
#define DIMD   256
#define NTOK   16384
#define NCODE  8192
#define NELEM  (NTOK * DIMD)

// fp32 project-GEMM tiling
#define BM 128
#define BK 128
#define BD 32
#define PAD 4
#define LDS_STRIDE (BM + PAD)

// distance kernels — two-pass, SHARED-B structure (round 10).
// History: forced occupancy (R1 spills), fused emission (R0/2/3), device
//   atomics in loop (R4: 425us), acc-split ILP (R6 spills), 32-tok/wave
//   (R7 halves intensity), per-wave async LDS staging (R8: no traffic
//   reduction -> pure cost).
// R10 theory: per-wave private B = 1 GB L2 reads/pass (~29us floor) co-
//   limits with MFMA (~29us). Fix: 4 waves share one 1024-code slice; B
//   staged 8KB/group into LDS ONCE per block (global_load_lds, linear,
//   double-buffered, one __syncthreads per group). B traffic /4, Xb /2,
//   frees the 64-reg B-dbuf (regs ~185 < wall), kills cross-wave combine.
#define CODES_PER_BLOCK 1024
#define TOK_PER_BLOCK   256
#define NGROUPS (CODES_PER_BLOCK / 16)          // 64
#define MARGIN 0.5f                   // > two-sided worst-case bf16 distance error
#define EBUF_CAP 1024                 // per-block emit staging

#define PROJ_BLOCKS ((NCODE / BM) * (DIMD / BK))   // 128
#define CONV_BLOCKS (NTOK / 4)                     // 4096

typedef float floatx4 __attribute__((ext_vector_type(4)));
typedef short short8  __attribute__((ext_vector_type(8)));
typedef unsigned int u32;

__device__ __forceinline__ unsigned short f2bf(float f) {
    unsigned u = __float_as_uint(f);
    unsigned r = (u + 0x7FFFu + ((u >> 16) & 1u)) >> 16;
    return (unsigned short)r;
}

// async 16B/lane global->LDS DMA: dest = wave-uniform base + lane*16 (linear)
__device__ __forceinline__ void gl_lds16(const void* g, void* l) {
    __builtin_amdgcn_global_load_lds(
        (const __attribute__((address_space(1))) u32*)g,
        (__attribute__((address_space(3))) u32*)l, 16, 0, 0);
}

// monotone float<->uint key (handles negative partial distances)
__device__ __forceinline__ unsigned fkey(float f) {
    unsigned u = __float_as_uint(f);
    return (u & 0x80000000u) ? ~u : (u | 0x80000000u);
}
__device__ __forceinline__ float funkey(unsigned k) {
    unsigned u = (k & 0x80000000u) ? (k & 0x7FFFFFFFu) : ~k;
    return __uint_as_float(u);
}

// fragment-major Cb index for element (row=code, col=k):
// block (row/16, col/32) of 512 elems; within: lane=(colsub/8)*16+(row%16), elem=col%8
__device__ __forceinline__ size_t cb2_idx(int row, int col) {
    return ((size_t)((row >> 4) * 8 + (col >> 5))) * 512
         + (size_t)((((col >> 3) & 3) * 16 + (row & 15)) * 8 + (col & 7));
}

// -------------------------------------------------------------------------
// Kernel 1 (fused prep): blocks [0,128) = codebook projection; blocks
// [128, 128+4096) = convx + all buffer inits. (round-9 form, unchanged)
// -------------------------------------------------------------------------
__global__ __launch_bounds__(256, 3)
void prep_kernel(const float* __restrict__ E, const float* __restrict__ W,
                 const float* __restrict__ bias, float* __restrict__ C,
                 unsigned short* __restrict__ Cb2,
                 float* __restrict__ cnormA, float* __restrict__ cnormB,
                 const float* __restrict__ X, float* __restrict__ xnorm,
                 unsigned short* __restrict__ Xb,
                 unsigned long long* __restrict__ fin,
                 unsigned* __restrict__ minkey,
                 unsigned* __restrict__ cnt, float* __restrict__ out)
{
    __shared__ float smem[2 * BD * LDS_STRIDE];

    const int bid = blockIdx.x;
    const int tid = threadIdx.x;

    if (bid >= PROJ_BLOCKS) {
        // ---- convx part + inits ----
        const int row0 = (bid - PROJ_BLOCKS) * 4;
        const int wave = tid >> 6;
        const int lane = tid & 63;
        const int row  = row0 + wave;
        float4 v = *(const float4*)&X[(size_t)row * DIMD + lane * 4];
        ushort4 h = {f2bf(v.x), f2bf(v.y), f2bf(v.z), f2bf(v.w)};
        *(ushort4*)&Xb[(size_t)row * DIMD + lane * 4] = h;
        float s = v.x * v.x + v.y * v.y + v.z * v.z + v.w * v.w;
#pragma unroll
        for (int off = 1; off < 64; off <<= 1) s += __shfl_xor(s, off);
        if (lane == 0) xnorm[row] = s;
        if (tid < 4) {
            fin[row0 + tid]    = ~0ull;
            minkey[row0 + tid] = ~0u;
        }
        if (bid == PROJ_BLOCKS && tid == 0) { *cnt = 0; out[NELEM] = 0.f; }
        return;
    }

    // ---- project part ----
    float* As = smem;
    float* Bs = smem + BD * LDS_STRIDE;

    const int tx  = tid & 15;
    const int ty  = tid >> 4;
    const int m0  = (bid & 63) * BM;
    const int j0  = (bid >> 6) * BK;

    const int srow = tid >> 3;
    const int scol = (tid & 7) * 4;

    float acc[8][8];
#pragma unroll
    for (int i = 0; i < 8; ++i)
#pragma unroll
        for (int j = 0; j < 8; ++j) acc[i][j] = 0.f;

    for (int dc = 0; dc < DIMD / BD; ++dc) {
        const int d0 = dc * BD;
        __syncthreads();
#pragma unroll
        for (int rr = 0; rr < 4; ++rr) {
            const int r = srow + rr * 32;
            float4 av = *(const float4*)&E[(size_t)(m0 + r) * DIMD + d0 + scol];
            As[(scol + 0) * LDS_STRIDE + r] = av.x;
            As[(scol + 1) * LDS_STRIDE + r] = av.y;
            As[(scol + 2) * LDS_STRIDE + r] = av.z;
            As[(scol + 3) * LDS_STRIDE + r] = av.w;
            float4 bv = *(const float4*)&W[(size_t)(j0 + r) * DIMD + d0 + scol];
            Bs[(scol + 0) * LDS_STRIDE + r] = bv.x;
            Bs[(scol + 1) * LDS_STRIDE + r] = bv.y;
            Bs[(scol + 2) * LDS_STRIDE + r] = bv.z;
            Bs[(scol + 3) * LDS_STRIDE + r] = bv.w;
        }
        __syncthreads();
#pragma unroll 4
        for (int d = 0; d < BD; ++d) {
            float4 a0 = *(float4*)&As[d * LDS_STRIDE + ty * 4];
            float4 a1 = *(float4*)&As[d * LDS_STRIDE + 64 + ty * 4];
            float4 b0 = *(float4*)&Bs[d * LDS_STRIDE + tx * 4];
            float4 b1 = *(float4*)&Bs[d * LDS_STRIDE + 64 + tx * 4];
            float a[8] = {a0.x, a0.y, a0.z, a0.w, a1.x, a1.y, a1.z, a1.w};
            float b[8] = {b0.x, b0.y, b0.z, b0.w, b1.x, b1.y, b1.z, b1.w};
#pragma unroll
            for (int i = 0; i < 8; ++i)
#pragma unroll
                for (int j = 0; j < 8; ++j) acc[i][j] = fmaf(a[i], b[j], acc[i][j]);
        }
    }

    __syncthreads();                       // done reading As/Bs; reuse smem
    float* red = smem;                     // [128 rows][16 tx]

    float4 bja = *(const float4*)&bias[j0 + tx * 4];
    float4 bjb = *(const float4*)&bias[j0 + 64 + tx * 4];
#pragma unroll
    for (int i = 0; i < 8; ++i) {
        const int mloc = (i < 4) ? (ty * 4 + i) : (64 + ty * 4 + (i - 4));
        const int row  = m0 + mloc;
        const size_t rbase = (size_t)row * DIMD;
        float o[8] = {acc[i][0] + bja.x, acc[i][1] + bja.y, acc[i][2] + bja.z, acc[i][3] + bja.w,
                      acc[i][4] + bjb.x, acc[i][5] + bjb.y, acc[i][6] + bjb.z, acc[i][7] + bjb.w};
        *(float4*)&C[rbase + j0 + tx * 4]      = *(float4*)&o[0];
        *(float4*)&C[rbase + j0 + 64 + tx * 4] = *(float4*)&o[4];
        ushort4 h0 = {f2bf(o[0]), f2bf(o[1]), f2bf(o[2]), f2bf(o[3])};
        ushort4 h1 = {f2bf(o[4]), f2bf(o[5]), f2bf(o[6]), f2bf(o[7])};
        *(ushort4*)&Cb2[cb2_idx(row, j0 + tx * 4)]      = h0;
        *(ushort4*)&Cb2[cb2_idx(row, j0 + 64 + tx * 4)] = h1;
        float p = 0.f;
#pragma unroll
        for (int j = 0; j < 8; ++j) p = fmaf(o[j], o[j], p);
        red[mloc * 16 + tx] = p;
    }
    __syncthreads();
    if (tid < 128) {
        float s = 0.f;
#pragma unroll
        for (int k = 0; k < 16; ++k) s += red[tid * 16 + k];
        float* dst = (j0 == 0) ? cnormA : cnormB;
        dst[m0 + tid] = s;                 // plain store, per-(block,row) unique
    }
}

// -------------------------------------------------------------------------
// Kernel 2a: PASS 1 — min-GEMM, shared-B. 4 waves × 64 tokens scan the
// same 1024-code slice; B group (8KB) DMA'd into LDS double-buffer, one
// __syncthreads per group. Each wave owns its tokens: direct atomicMin.
// -------------------------------------------------------------------------
__global__ __launch_bounds__(256, 2)
void dist_min_kernel(const unsigned short* __restrict__ Xb,
                     const unsigned short* __restrict__ Cb2,
                     const float* __restrict__ cnormA,
                     const float* __restrict__ cnormB,
                     unsigned* __restrict__ minkey)
{
    __shared__ short Bls[2][4096];             // 16 KB double buffer
    __shared__ float cnl[CODES_PER_BLOCK];     // 4 KB

    const int tid  = threadIdx.x;
    const int lane = tid & 63;
    const int wv   = tid >> 6;
    const int l15  = lane & 15;
    const int quad = lane >> 4;
    const int tok0 = blockIdx.x * TOK_PER_BLOCK + wv * 64;
    const int cbase = blockIdx.y * CODES_PER_BLOCK;

    // cnorm slice -> LDS (plain f4 loads + stores; once)
    {
        const int t4 = tid * 4;
        float4 va = *(const float4*)&cnormA[cbase + t4];
        float4 vb = *(const float4*)&cnormB[cbase + t4];
        cnl[t4 + 0] = va.x + vb.x;
        cnl[t4 + 1] = va.y + vb.y;
        cnl[t4 + 2] = va.z + vb.z;
        cnl[t4 + 3] = va.w + vb.w;
    }

    // B stage: group g = 8 KB contiguous (fragment-major); wave wv DMAs
    // its 2 KB quarter: 2 x 1KB instrs, linear dest (rule #21).
    const unsigned short* bsrc = Cb2 + (size_t)cbase * DIMD;
    auto STAGE = [&](int g) {
        const unsigned short* s = bsrc + (size_t)g * 4096 + wv * 1024 + lane * 8;
        short* d = &Bls[g & 1][wv * 1024];
        gl_lds16(s,       d);
        gl_lds16(s + 512, d + 512);
    };
    STAGE(0);
    STAGE(1);

    // A fragments: 64 tokens x 256 k, register-resident (128 regs)
    short8 a[4][8];
#pragma unroll
    for (int i = 0; i < 4; ++i) {
        const unsigned short* ap = Xb + (size_t)(tok0 + i * 16 + l15) * DIMD + quad * 8;
#pragma unroll
        for (int ks = 0; ks < 8; ++ks)
            a[i][ks] = *(const short8*)(ap + ks * 32);
    }

    float runv[16];
#pragma unroll
    for (int s = 0; s < 16; ++s) runv[s] = 3.4e38f;

    __syncthreads();   // cnl + staged groups 0,1 complete (full drain, once)

    for (int g = 0; g < NGROUPS; ++g) {
        const short* bp = &Bls[g & 1][lane * 8];
        short8 bc[8];
#pragma unroll
        for (int ks = 0; ks < 8; ++ks) bc[ks] = *(const short8*)(bp + ks * 512);
        const float cnc = cnl[g * 16 + l15];

        floatx4 acc[4];
#pragma unroll
        for (int i = 0; i < 4; ++i) acc[i] = (floatx4){0.f, 0.f, 0.f, 0.f};
#pragma unroll
        for (int ks = 0; ks < 8; ++ks)
#pragma unroll
            for (int i = 0; i < 4; ++i)
                acc[i] = __builtin_amdgcn_mfma_f32_16x16x32_bf16(a[i][ks], bc[ks], acc[i], 0, 0, 0);

#pragma unroll
        for (int i = 0; i < 4; ++i)
#pragma unroll
            for (int r = 0; r < 4; ++r)
                runv[i * 4 + r] = fminf(runv[i * 4 + r], fmaf(-2.f, acc[i][r], cnc));

        // all waves finished reading buf[g&1] (data already in regs);
        // barrier also drains the DMA for group g+1 issued last iteration.
        __syncthreads();
        if (g + 2 < NGROUPS) STAGE(g + 2);   // overwrite buf[g&1]
    }

    // per-wave final: min over the 16 code-lanes, then direct atomicMin
#pragma unroll
    for (int s = 0; s < 16; ++s) {
        float m = runv[s];
#pragma unroll
        for (int off = 1; off < 16; off <<= 1) m = fminf(m, __shfl_xor(m, off));
        runv[s] = m;
    }
    if (l15 == 0) {
#pragma unroll
        for (int i = 0; i < 4; ++i)
#pragma unroll
            for (int r = 0; r < 4; ++r)
                atomicMin(&minkey[tok0 + i * 16 + quad * 4 + r], fkey(runv[i * 4 + r]));
    }
}

// -------------------------------------------------------------------------
// Kernel 2b: PASS 2 — emit vs FINAL global per-token threshold, shared-B
// structure. Rare hits staged in block LDS; ONE device atomic per block.
// -------------------------------------------------------------------------
__global__ __launch_bounds__(256, 2)
void dist_emit_kernel(const unsigned short* __restrict__ Xb,
                      const unsigned short* __restrict__ Cb2,
                      const float* __restrict__ cnormA,
                      const float* __restrict__ cnormB,
                      const unsigned* __restrict__ minkey,
                      unsigned* __restrict__ list, unsigned* __restrict__ count,
                      unsigned cap)
{
    __shared__ short Bls[2][4096];             // 16 KB
    __shared__ float cnl[CODES_PER_BLOCK];     // 4 KB
    __shared__ float tokthr[TOK_PER_BLOCK];    // 1 KB
    __shared__ unsigned ebuf[EBUF_CAP];        // 4 KB
    __shared__ unsigned ecnt, gbase;

    const int tid  = threadIdx.x;
    const int lane = tid & 63;
    const int wv   = tid >> 6;
    const int l15  = lane & 15;
    const int quad = lane >> 4;
    const int tok0b = blockIdx.x * TOK_PER_BLOCK;
    const int tok0 = tok0b + wv * 64;
    const int cbase = blockIdx.y * CODES_PER_BLOCK;

    {
        const int t4 = tid * 4;
        float4 va = *(const float4*)&cnormA[cbase + t4];
        float4 vb = *(const float4*)&cnormB[cbase + t4];
        cnl[t4 + 0] = va.x + vb.x;
        cnl[t4 + 1] = va.y + vb.y;
        cnl[t4 + 2] = va.z + vb.z;
        cnl[t4 + 3] = va.w + vb.w;
    }
    tokthr[tid] = funkey(minkey[tok0b + tid]) + MARGIN;
    if (tid == 0) ecnt = 0;

    const unsigned short* bsrc = Cb2 + (size_t)cbase * DIMD;
    auto STAGE = [&](int g) {
        const unsigned short* s = bsrc + (size_t)g * 4096 + wv * 1024 + lane * 8;
        short* d = &Bls[g & 1][wv * 1024];
        gl_lds16(s,       d);
        gl_lds16(s + 512, d + 512);
    };
    STAGE(0);
    STAGE(1);

    short8 a[4][8];
#pragma unroll
    for (int i = 0; i < 4; ++i) {
        const unsigned short* ap = Xb + (size_t)(tok0 + i * 16 + l15) * DIMD + quad * 8;
#pragma unroll
        for (int ks = 0; ks < 8; ++ks)
            a[i][ks] = *(const short8*)(ap + ks * 32);
    }

    __syncthreads();   // cnl/tokthr/ecnt + groups 0,1 complete

    // fixed per-slot thresholds in registers (static indexing only)
    float thr[16];
#pragma unroll
    for (int i = 0; i < 4; ++i)
#pragma unroll
        for (int r = 0; r < 4; ++r)
            thr[i * 4 + r] = tokthr[wv * 64 + i * 16 + quad * 4 + r];

    for (int g = 0; g < NGROUPS; ++g) {
        const int code0 = cbase + g * 16;
        const short* bp = &Bls[g & 1][lane * 8];
        short8 bc[8];
#pragma unroll
        for (int ks = 0; ks < 8; ++ks) bc[ks] = *(const short8*)(bp + ks * 512);
        const float cnc = cnl[g * 16 + l15];

        floatx4 acc[4];
#pragma unroll
        for (int i = 0; i < 4; ++i) acc[i] = (floatx4){0.f, 0.f, 0.f, 0.f};
#pragma unroll
        for (int ks = 0; ks < 8; ++ks)
#pragma unroll
            for (int i = 0; i < 4; ++i)
                acc[i] = __builtin_amdgcn_mfma_f32_16x16x32_bf16(a[i][ks], bc[ks], acc[i], 0, 0, 0);

        unsigned mask = 0;
#pragma unroll
        for (int i = 0; i < 4; ++i)
#pragma unroll
            for (int r = 0; r < 4; ++r) {
                const float dd = fmaf(-2.f, acc[i][r], cnc);
                if (dd < thr[i * 4 + r]) mask |= (1u << (i * 4 + r));
            }

        if (__any(mask != 0)) {
            if (mask) {
                unsigned pos = atomicAdd(&ecnt, (unsigned)__popc(mask));
#pragma unroll
                for (int i = 0; i < 4; ++i)
#pragma unroll
                    for (int r = 0; r < 4; ++r) {
                        const int s = i * 4 + r;
                        if (mask & (1u << s)) {
                            const unsigned token = tok0 + i * 16 + quad * 4 + r;
                            const unsigned entry = (token << 13) | (unsigned)(code0 + l15);
                            if (pos < EBUF_CAP) ebuf[pos] = entry;
                            else { unsigned gp = atomicAdd(count, 1u); if (gp < cap) list[gp] = entry; }
                            ++pos;
                        }
                    }
            }
        }

        __syncthreads();
        if (g + 2 < NGROUPS) STAGE(g + 2);
    }

    __syncthreads();
    const unsigned n = (ecnt < EBUF_CAP) ? ecnt : EBUF_CAP;
    if (tid == 0) gbase = atomicAdd(count, n);
    __syncthreads();
    const unsigned gb = gbase;
    for (unsigned i = tid; i < n; i += 256) {
        const unsigned p = gb + i;
        if (p < cap) list[p] = ebuf[i];
    }
}

// -------------------------------------------------------------------------
// Kernel 3: exact fp32 rescore. 16-lane groups, 4 candidates per wave.
// Packed (d_bits<<32 | code) atomicMin -> lowest-index tie-break.
// -------------------------------------------------------------------------
__global__ __launch_bounds__(256)
void rescore_kernel(const float* __restrict__ X, const float* __restrict__ C,
                    const float* __restrict__ xnorm,
                    const float* __restrict__ cnormA,
                    const float* __restrict__ cnormB,
                    const unsigned* __restrict__ list, const unsigned* __restrict__ count,
                    unsigned cap, unsigned long long* __restrict__ fin)
{
    const int lane = threadIdx.x & 63;
    const int g16  = lane & 15;
    const int sub  = lane >> 4;
    const int gid  = ((blockIdx.x * 256 + threadIdx.x) >> 6) * 4 + sub;
    const int ng   = ((gridDim.x * 256) >> 6) * 4;
    unsigned n = *count; if (n > cap) n = cap;

    for (unsigned c = gid; c < n; c += ng) {
        const unsigned e = list[c];
        const unsigned tok = e >> 13, code = e & 8191u;
        const float* xr = &X[(size_t)tok * DIMD];
        const float* cr = &C[(size_t)code * DIMD];
        float dot = 0.f;
#pragma unroll
        for (int r = 0; r < 4; ++r) {
            float4 x4 = *(const float4*)&xr[r * 64 + g16 * 4];
            float4 c4 = *(const float4*)&cr[r * 64 + g16 * 4];
            dot = fmaf(x4.x, c4.x, dot);
            dot = fmaf(x4.y, c4.y, dot);
            dot = fmaf(x4.z, c4.z, dot);
            dot = fmaf(x4.w, c4.w, dot);
        }
#pragma unroll
        for (int d = 1; d < 16; d <<= 1) dot += __shfl_xor(dot, d);
        if (g16 == 0) {
            const float dd = xnorm[tok] + (cnormA[code] + cnormB[code]) - 2.f * dot;
            const unsigned long long p =
                ((unsigned long long)__float_as_uint(dd) << 32) | code;
            atomicMin(&fin[tok], p);
        }
    }
}

// -------------------------------------------------------------------------
// Kernel 4: gather winner, straight-through output, loss. One atomic/block.
// -------------------------------------------------------------------------
__global__ __launch_bounds__(256)
void finalize_kernel(const float* __restrict__ X, const float* __restrict__ C,
                     const unsigned long long* __restrict__ fin,
                     float* __restrict__ out)
{
    __shared__ float part[4];
    const int lane = threadIdx.x & 63;
    const int wv   = threadIdx.x >> 6;
    const int t0   = blockIdx.x * 64;

    float local = 0.f;
    for (int it = 0; it < 16; ++it) {
        const int t = t0 + wv * 16 + it;
        const unsigned code = (unsigned)(fin[t] & 0xFFFFFFFFull);
        float4 c4 = *(const float4*)&C[(size_t)code * DIMD + lane * 4];
        float4 x4 = *(const float4*)&X[(size_t)t * DIMD + lane * 4];
        float4 w  = {c4.x - x4.x, c4.y - x4.y, c4.z - x4.z, c4.w - x4.w};
        local += w.x * w.x + w.y * w.y + w.z * w.z + w.w * w.w;
        float4 zq = {x4.x + w.x, x4.y + w.y, x4.z + w.z, x4.w + w.w};
        *(float4*)&out[(size_t)t * DIMD + lane * 4] = zq;
        if (lane == 0) out[NELEM + 1 + t] = (float)code;
    }
#pragma unroll
    for (int off = 1; off < 64; off <<= 1) local += __shfl_xor(local, off);
    if (lane == 0) part[wv] = local;
    __syncthreads();
    if (threadIdx.x == 0) {
        const float s = part[0] + part[1] + part[2] + part[3];
        atomicAdd(&out[NELEM], s * (1.25f / (float)NELEM));
    }
}

// -------------------------------------------------------------------------
extern "C" void kernel_launch(void* const* d_in, const int* in_sizes, int n_in,
                              void* d_out, int out_size, void* d_ws, size_t ws_size,
                              hipStream_t stream)
{
    const float* X = (const float*)d_in[0];
    const float* E = (const float*)d_in[1];
    const float* W = (const float*)d_in[2];
    const float* b = (const float*)d_in[3];
    float* out = (float*)d_out;

    char* w = (char*)d_ws;
    float* C            = (float*)w;           w += (size_t)NCODE * DIMD * 4;
    unsigned short* Xb  = (unsigned short*)w;  w += (size_t)NTOK * DIMD * 2;
    unsigned short* Cb2 = (unsigned short*)w;  w += (size_t)NCODE * DIMD * 2;
    float* xnorm        = (float*)w;           w += (size_t)NTOK * 4;
    float* cnormA       = (float*)w;           w += (size_t)NCODE * 4;
    float* cnormB       = (float*)w;           w += (size_t)NCODE * 4;
    unsigned* cnt       = (unsigned*)w;        w += 256;
    unsigned long long* fin = (unsigned long long*)w; w += (size_t)NTOK * 8;
    unsigned* minkey    = (unsigned*)w;        w += (size_t)NTOK * 4;
    unsigned* list      = (unsigned*)w;

    size_t used = (size_t)(w - (char*)d_ws);
    size_t avail = (ws_size > used) ? (ws_size - used) / 4 : 0;
    unsigned cap = (unsigned)((avail > 16777216u) ? 16777216u : avail);

    // 5 dispatches, zero memsets.
    prep_kernel<<<PROJ_BLOCKS + CONV_BLOCKS, 256, 0, stream>>>(
        E, W, b, C, Cb2, cnormA, cnormB, X, xnorm, Xb, fin, minkey, cnt, out);
    dist_min_kernel<<<dim3(NTOK / TOK_PER_BLOCK, NCODE / CODES_PER_BLOCK), 256, 0, stream>>>(
        Xb, Cb2, cnormA, cnormB, minkey);
    dist_emit_kernel<<<dim3(NTOK / TOK_PER_BLOCK, NCODE / CODES_PER_BLOCK), 256, 0, stream>>>(
        Xb, Cb2, cnormA, cnormB, minkey, list, cnt, cap);
    rescore_kernel<<<1024, 256, 0, stream>>>(X, C, xnorm, cnormA, cnormB, list, cnt, cap, fin);
    finalize_kernel<<<NTOK / 64, 256, 0, stream>>>(X, C, fin, out);
}

// Round 11
// 273.180 us; speedup vs baseline: 1.1351x; 1.0019x over previous
//
#include <hip/hip_runtime.h>

// Problem constants
#define DIMD   256
#define NTOK   16384
#define NCODE  8192
#define NELEM  (NTOK * DIMD)

// fp32 project-GEMM tiling
#define BM 128
#define BK 128
#define BD 32
#define PAD 4
#define LDS_STRIDE (BM + PAD)

// distance kernels — per-pass measured-best structures (round 11):
//   dist_min : shared-B (R10) — 4 waves share a 1024-code slice, B DMA'd
//              to LDS dbuf, 1 barrier/group. Divergence-free -> barrier
//              cheap, B L2 traffic /4. Measured ~8us faster than private.
//   dist_emit: private-B (R9) — per-wave register B-dbuf, barrier-free.
//              Emission divergence makes per-group barriers costly
//              (R10 A/B: shared-B emit 91.4 vs private 87.5). Reverted.
// History of dead ends: forced occupancy (R1 spills), fused emission
//   (R0/2/3), device atomics in loop (R4: 425us), acc-split ILP (R6
//   spills), 32-tok/wave (R7 halves intensity), per-wave async LDS (R8).
#define MARGIN 0.5f                   // > two-sided worst-case bf16 distance error
#define EBUF_CAP 1024                 // per-block emit staging

// shared-B (min) geometry
#define CODES_PER_BLOCK 1024
#define TOK_PER_BLOCK   256
#define MIN_NGROUPS (CODES_PER_BLOCK / 16)      // 64
// private-B (emit) geometry
#define EM_SPLITS 4
#define EM_CPW (NCODE / EM_SPLITS / 4)          // 512
#define EM_NGROUPS (EM_CPW / 16)                // 32

#define PROJ_BLOCKS ((NCODE / BM) * (DIMD / BK))   // 128
#define CONV_BLOCKS (NTOK / 4)                     // 4096

typedef float floatx4 __attribute__((ext_vector_type(4)));
typedef short short8  __attribute__((ext_vector_type(8)));
typedef unsigned int u32;

__device__ __forceinline__ unsigned short f2bf(float f) {
    unsigned u = __float_as_uint(f);
    unsigned r = (u + 0x7FFFu + ((u >> 16) & 1u)) >> 16;
    return (unsigned short)r;
}

// async 16B/lane global->LDS DMA: dest = wave-uniform base + lane*16 (linear)
__device__ __forceinline__ void gl_lds16(const void* g, void* l) {
    __builtin_amdgcn_global_load_lds(
        (const __attribute__((address_space(1))) u32*)g,
        (__attribute__((address_space(3))) u32*)l, 16, 0, 0);
}

// monotone float<->uint key (handles negative partial distances)
__device__ __forceinline__ unsigned fkey(float f) {
    unsigned u = __float_as_uint(f);
    return (u & 0x80000000u) ? ~u : (u | 0x80000000u);
}
__device__ __forceinline__ float funkey(unsigned k) {
    unsigned u = (k & 0x80000000u) ? (k & 0x7FFFFFFFu) : ~k;
    return __uint_as_float(u);
}

// fragment-major Cb index for element (row=code, col=k):
// block (row/16, col/32) of 512 elems; within: lane=(colsub/8)*16+(row%16), elem=col%8
__device__ __forceinline__ size_t cb2_idx(int row, int col) {
    return ((size_t)((row >> 4) * 8 + (col >> 5))) * 512
         + (size_t)((((col >> 3) & 3) * 16 + (row & 15)) * 8 + (col & 7));
}

// -------------------------------------------------------------------------
// Kernel 1 (fused prep): blocks [0,128) = codebook projection; blocks
// [128, 128+4096) = convx + all buffer inits. (round-9 form, unchanged)
// -------------------------------------------------------------------------
__global__ __launch_bounds__(256, 3)
void prep_kernel(const float* __restrict__ E, const float* __restrict__ W,
                 const float* __restrict__ bias, float* __restrict__ C,
                 unsigned short* __restrict__ Cb2,
                 float* __restrict__ cnormA, float* __restrict__ cnormB,
                 const float* __restrict__ X, float* __restrict__ xnorm,
                 unsigned short* __restrict__ Xb,
                 unsigned long long* __restrict__ fin,
                 unsigned* __restrict__ minkey,
                 unsigned* __restrict__ cnt, float* __restrict__ out)
{
    __shared__ float smem[2 * BD * LDS_STRIDE];

    const int bid = blockIdx.x;
    const int tid = threadIdx.x;

    if (bid >= PROJ_BLOCKS) {
        // ---- convx part + inits ----
        const int row0 = (bid - PROJ_BLOCKS) * 4;
        const int wave = tid >> 6;
        const int lane = tid & 63;
        const int row  = row0 + wave;
        float4 v = *(const float4*)&X[(size_t)row * DIMD + lane * 4];
        ushort4 h = {f2bf(v.x), f2bf(v.y), f2bf(v.z), f2bf(v.w)};
        *(ushort4*)&Xb[(size_t)row * DIMD + lane * 4] = h;
        float s = v.x * v.x + v.y * v.y + v.z * v.z + v.w * v.w;
#pragma unroll
        for (int off = 1; off < 64; off <<= 1) s += __shfl_xor(s, off);
        if (lane == 0) xnorm[row] = s;
        if (tid < 4) {
            fin[row0 + tid]    = ~0ull;
            minkey[row0 + tid] = ~0u;
        }
        if (bid == PROJ_BLOCKS && tid == 0) { *cnt = 0; out[NELEM] = 0.f; }
        return;
    }

    // ---- project part ----
    float* As = smem;
    float* Bs = smem + BD * LDS_STRIDE;

    const int tx  = tid & 15;
    const int ty  = tid >> 4;
    const int m0  = (bid & 63) * BM;
    const int j0  = (bid >> 6) * BK;

    const int srow = tid >> 3;
    const int scol = (tid & 7) * 4;

    float acc[8][8];
#pragma unroll
    for (int i = 0; i < 8; ++i)
#pragma unroll
        for (int j = 0; j < 8; ++j) acc[i][j] = 0.f;

    for (int dc = 0; dc < DIMD / BD; ++dc) {
        const int d0 = dc * BD;
        __syncthreads();
#pragma unroll
        for (int rr = 0; rr < 4; ++rr) {
            const int r = srow + rr * 32;
            float4 av = *(const float4*)&E[(size_t)(m0 + r) * DIMD + d0 + scol];
            As[(scol + 0) * LDS_STRIDE + r] = av.x;
            As[(scol + 1) * LDS_STRIDE + r] = av.y;
            As[(scol + 2) * LDS_STRIDE + r] = av.z;
            As[(scol + 3) * LDS_STRIDE + r] = av.w;
            float4 bv = *(const float4*)&W[(size_t)(j0 + r) * DIMD + d0 + scol];
            Bs[(scol + 0) * LDS_STRIDE + r] = bv.x;
            Bs[(scol + 1) * LDS_STRIDE + r] = bv.y;
            Bs[(scol + 2) * LDS_STRIDE + r] = bv.z;
            Bs[(scol + 3) * LDS_STRIDE + r] = bv.w;
        }
        __syncthreads();
#pragma unroll 4
        for (int d = 0; d < BD; ++d) {
            float4 a0 = *(float4*)&As[d * LDS_STRIDE + ty * 4];
            float4 a1 = *(float4*)&As[d * LDS_STRIDE + 64 + ty * 4];
            float4 b0 = *(float4*)&Bs[d * LDS_STRIDE + tx * 4];
            float4 b1 = *(float4*)&Bs[d * LDS_STRIDE + 64 + tx * 4];
            float a[8] = {a0.x, a0.y, a0.z, a0.w, a1.x, a1.y, a1.z, a1.w};
            float b[8] = {b0.x, b0.y, b0.z, b0.w, b1.x, b1.y, b1.z, b1.w};
#pragma unroll
            for (int i = 0; i < 8; ++i)
#pragma unroll
                for (int j = 0; j < 8; ++j) acc[i][j] = fmaf(a[i], b[j], acc[i][j]);
        }
    }

    __syncthreads();                       // done reading As/Bs; reuse smem
    float* red = smem;                     // [128 rows][16 tx]

    float4 bja = *(const float4*)&bias[j0 + tx * 4];
    float4 bjb = *(const float4*)&bias[j0 + 64 + tx * 4];
#pragma unroll
    for (int i = 0; i < 8; ++i) {
        const int mloc = (i < 4) ? (ty * 4 + i) : (64 + ty * 4 + (i - 4));
        const int row  = m0 + mloc;
        const size_t rbase = (size_t)row * DIMD;
        float o[8] = {acc[i][0] + bja.x, acc[i][1] + bja.y, acc[i][2] + bja.z, acc[i][3] + bja.w,
                      acc[i][4] + bjb.x, acc[i][5] + bjb.y, acc[i][6] + bjb.z, acc[i][7] + bjb.w};
        *(float4*)&C[rbase + j0 + tx * 4]      = *(float4*)&o[0];
        *(float4*)&C[rbase + j0 + 64 + tx * 4] = *(float4*)&o[4];
        ushort4 h0 = {f2bf(o[0]), f2bf(o[1]), f2bf(o[2]), f2bf(o[3])};
        ushort4 h1 = {f2bf(o[4]), f2bf(o[5]), f2bf(o[6]), f2bf(o[7])};
        *(ushort4*)&Cb2[cb2_idx(row, j0 + tx * 4)]      = h0;
        *(ushort4*)&Cb2[cb2_idx(row, j0 + 64 + tx * 4)] = h1;
        float p = 0.f;
#pragma unroll
        for (int j = 0; j < 8; ++j) p = fmaf(o[j], o[j], p);
        red[mloc * 16 + tx] = p;
    }
    __syncthreads();
    if (tid < 128) {
        float s = 0.f;
#pragma unroll
        for (int k = 0; k < 16; ++k) s += red[tid * 16 + k];
        float* dst = (j0 == 0) ? cnormA : cnormB;
        dst[m0 + tid] = s;                 // plain store, per-(block,row) unique
    }
}

// -------------------------------------------------------------------------
// Kernel 2a: PASS 1 — min-GEMM, SHARED-B (R10 measured-best form).
// 4 waves × 64 tokens scan the same 1024-code slice; B group (8KB) DMA'd
// into LDS double-buffer, one __syncthreads per group. Direct atomicMin.
// -------------------------------------------------------------------------
__global__ __launch_bounds__(256, 2)
void dist_min_kernel(const unsigned short* __restrict__ Xb,
                     const unsigned short* __restrict__ Cb2,
                     const float* __restrict__ cnormA,
                     const float* __restrict__ cnormB,
                     unsigned* __restrict__ minkey)
{
    __shared__ short Bls[2][4096];             // 16 KB double buffer
    __shared__ float cnl[CODES_PER_BLOCK];     // 4 KB

    const int tid  = threadIdx.x;
    const int lane = tid & 63;
    const int wv   = tid >> 6;
    const int l15  = lane & 15;
    const int quad = lane >> 4;
    const int tok0 = blockIdx.x * TOK_PER_BLOCK + wv * 64;
    const int cbase = blockIdx.y * CODES_PER_BLOCK;

    {
        const int t4 = tid * 4;
        float4 va = *(const float4*)&cnormA[cbase + t4];
        float4 vb = *(const float4*)&cnormB[cbase + t4];
        cnl[t4 + 0] = va.x + vb.x;
        cnl[t4 + 1] = va.y + vb.y;
        cnl[t4 + 2] = va.z + vb.z;
        cnl[t4 + 3] = va.w + vb.w;
    }

    const unsigned short* bsrc = Cb2 + (size_t)cbase * DIMD;
    auto STAGE = [&](int g) {
        const unsigned short* s = bsrc + (size_t)g * 4096 + wv * 1024 + lane * 8;
        short* d = &Bls[g & 1][wv * 1024];
        gl_lds16(s,       d);
        gl_lds16(s + 512, d + 512);
    };
    STAGE(0);
    STAGE(1);

    short8 a[4][8];
#pragma unroll
    for (int i = 0; i < 4; ++i) {
        const unsigned short* ap = Xb + (size_t)(tok0 + i * 16 + l15) * DIMD + quad * 8;
#pragma unroll
        for (int ks = 0; ks < 8; ++ks)
            a[i][ks] = *(const short8*)(ap + ks * 32);
    }

    float runv[16];
#pragma unroll
    for (int s = 0; s < 16; ++s) runv[s] = 3.4e38f;

    __syncthreads();   // cnl + staged groups 0,1 complete

    for (int g = 0; g < MIN_NGROUPS; ++g) {
        const short* bp = &Bls[g & 1][lane * 8];
        short8 bc[8];
#pragma unroll
        for (int ks = 0; ks < 8; ++ks) bc[ks] = *(const short8*)(bp + ks * 512);
        const float cnc = cnl[g * 16 + l15];

        floatx4 acc[4];
#pragma unroll
        for (int i = 0; i < 4; ++i) acc[i] = (floatx4){0.f, 0.f, 0.f, 0.f};
#pragma unroll
        for (int ks = 0; ks < 8; ++ks)
#pragma unroll
            for (int i = 0; i < 4; ++i)
                acc[i] = __builtin_amdgcn_mfma_f32_16x16x32_bf16(a[i][ks], bc[ks], acc[i], 0, 0, 0);

#pragma unroll
        for (int i = 0; i < 4; ++i)
#pragma unroll
            for (int r = 0; r < 4; ++r)
                runv[i * 4 + r] = fminf(runv[i * 4 + r], fmaf(-2.f, acc[i][r], cnc));

        __syncthreads();
        if (g + 2 < MIN_NGROUPS) STAGE(g + 2);
    }

#pragma unroll
    for (int s = 0; s < 16; ++s) {
        float m = runv[s];
#pragma unroll
        for (int off = 1; off < 16; off <<= 1) m = fminf(m, __shfl_xor(m, off));
        runv[s] = m;
    }
    if (l15 == 0) {
#pragma unroll
        for (int i = 0; i < 4; ++i)
#pragma unroll
            for (int r = 0; r < 4; ++r)
                atomicMin(&minkey[tok0 + i * 16 + quad * 4 + r], fkey(runv[i * 4 + r]));
    }
}

// -------------------------------------------------------------------------
// Kernel 2b: PASS 2 — emit vs FINAL threshold, PRIVATE-B register-dbuf
// (R9 measured-best form: barrier-free, divergence-tolerant). Rare hits
// staged in block LDS; ONE device atomic per block.
// -------------------------------------------------------------------------
__global__ __launch_bounds__(256, 2)
void dist_emit_kernel(const unsigned short* __restrict__ Xb,
                      const unsigned short* __restrict__ Cb2,
                      const float* __restrict__ cnormA,
                      const float* __restrict__ cnormB,
                      const unsigned* __restrict__ minkey,
                      unsigned* __restrict__ list, unsigned* __restrict__ count,
                      unsigned cap)
{
    __shared__ float tokthr[64];
    __shared__ unsigned ebuf[EBUF_CAP];
    __shared__ unsigned ecnt, gbase;

    const int tid  = threadIdx.x;
    const int lane = tid & 63;
    const int wv   = tid >> 6;
    const int l15  = lane & 15;
    const int quad = lane >> 4;
    const int tok0 = blockIdx.x * 64;
    const int cbase = blockIdx.y * (NCODE / EM_SPLITS) + wv * EM_CPW;

    if (tid == 0) ecnt = 0;
    if (tid < 64) tokthr[tid] = funkey(minkey[tok0 + tid]) + MARGIN;
    __syncthreads();

    short8 a[4][8];
#pragma unroll
    for (int i = 0; i < 4; ++i) {
        const unsigned short* ap = Xb + (size_t)(tok0 + i * 16 + l15) * DIMD + quad * 8;
#pragma unroll
        for (int ks = 0; ks < 8; ++ks)
            a[i][ks] = *(const short8*)(ap + ks * 32);
    }

    float thr[16];
#pragma unroll
    for (int i = 0; i < 4; ++i)
#pragma unroll
        for (int r = 0; r < 4; ++r)
            thr[i * 4 + r] = tokthr[i * 16 + quad * 4 + r];

    const unsigned short* bp0 = Cb2 + (size_t)cbase * DIMD + lane * 8;

    short8 breg[2][8];
    float  cnr[2];
#pragma unroll
    for (int ks = 0; ks < 8; ++ks) breg[0][ks] = *(const short8*)(bp0 + ks * 512);
    cnr[0] = cnormA[cbase + l15] + cnormB[cbase + l15];

    auto group_body = [&](int g, short8 (&bc)[8], short8 (&bn)[8],
                          float cnc, float& cnn) {
        const int code0 = cbase + g * 16;
        if (g + 1 < EM_NGROUPS) {
            const unsigned short* bpn = bp0 + (size_t)(g + 1) * 4096;
#pragma unroll
            for (int ks = 0; ks < 8; ++ks) bn[ks] = *(const short8*)(bpn + ks * 512);
            const int cnx = code0 + 16 + l15;
            cnn = cnormA[cnx] + cnormB[cnx];
        }

        floatx4 acc[4];
#pragma unroll
        for (int i = 0; i < 4; ++i) acc[i] = (floatx4){0.f, 0.f, 0.f, 0.f};
#pragma unroll
        for (int ks = 0; ks < 8; ++ks)
#pragma unroll
            for (int i = 0; i < 4; ++i)
                acc[i] = __builtin_amdgcn_mfma_f32_16x16x32_bf16(a[i][ks], bc[ks], acc[i], 0, 0, 0);

        unsigned mask = 0;
#pragma unroll
        for (int i = 0; i < 4; ++i)
#pragma unroll
            for (int r = 0; r < 4; ++r) {
                const float dd = fmaf(-2.f, acc[i][r], cnc);
                if (dd < thr[i * 4 + r]) mask |= (1u << (i * 4 + r));
            }

        if (__any(mask != 0)) {
            if (mask) {
                unsigned pos = atomicAdd(&ecnt, (unsigned)__popc(mask));
#pragma unroll
                for (int i = 0; i < 4; ++i)
#pragma unroll
                    for (int r = 0; r < 4; ++r) {
                        const int s = i * 4 + r;
                        if (mask & (1u << s)) {
                            const unsigned token = tok0 + i * 16 + quad * 4 + r;
                            const unsigned entry = (token << 13) | (unsigned)(code0 + l15);
                            if (pos < EBUF_CAP) ebuf[pos] = entry;
                            else { unsigned gp = atomicAdd(count, 1u); if (gp < cap) list[gp] = entry; }
                            ++pos;
                        }
                    }
            }
        }
    };

    for (int gg = 0; gg < EM_NGROUPS; gg += 2) {
        group_body(gg,     breg[0], breg[1], cnr[0], cnr[1]);
        group_body(gg + 1, breg[1], breg[0], cnr[1], cnr[0]);
    }

    __syncthreads();
    const unsigned n = (ecnt < EBUF_CAP) ? ecnt : EBUF_CAP;
    if (tid == 0) gbase = atomicAdd(count, n);
    __syncthreads();
    const unsigned gb = gbase;
    for (unsigned i = tid; i < n; i += 256) {
        const unsigned p = gb + i;
        if (p < cap) list[p] = ebuf[i];
    }
}

// -------------------------------------------------------------------------
// Kernel 3: exact fp32 rescore. 16-lane groups, 4 candidates per wave.
// Packed (d_bits<<32 | code) atomicMin -> lowest-index tie-break.
// -------------------------------------------------------------------------
__global__ __launch_bounds__(256)
void rescore_kernel(const float* __restrict__ X, const float* __restrict__ C,
                    const float* __restrict__ xnorm,
                    const float* __restrict__ cnormA,
                    const float* __restrict__ cnormB,
                    const unsigned* __restrict__ list, const unsigned* __restrict__ count,
                    unsigned cap, unsigned long long* __restrict__ fin)
{
    const int lane = threadIdx.x & 63;
    const int g16  = lane & 15;
    const int sub  = lane >> 4;
    const int gid  = ((blockIdx.x * 256 + threadIdx.x) >> 6) * 4 + sub;
    const int ng   = ((gridDim.x * 256) >> 6) * 4;
    unsigned n = *count; if (n > cap) n = cap;

    for (unsigned c = gid; c < n; c += ng) {
        const unsigned e = list[c];
        const unsigned tok = e >> 13, code = e & 8191u;
        const float* xr = &X[(size_t)tok * DIMD];
        const float* cr = &C[(size_t)code * DIMD];
        float dot = 0.f;
#pragma unroll
        for (int r = 0; r < 4; ++r) {
            float4 x4 = *(const float4*)&xr[r * 64 + g16 * 4];
            float4 c4 = *(const float4*)&cr[r * 64 + g16 * 4];
            dot = fmaf(x4.x, c4.x, dot);
            dot = fmaf(x4.y, c4.y, dot);
            dot = fmaf(x4.z, c4.z, dot);
            dot = fmaf(x4.w, c4.w, dot);
        }
#pragma unroll
        for (int d = 1; d < 16; d <<= 1) dot += __shfl_xor(dot, d);
        if (g16 == 0) {
            const float dd = xnorm[tok] + (cnormA[code] + cnormB[code]) - 2.f * dot;
            const unsigned long long p =
                ((unsigned long long)__float_as_uint(dd) << 32) | code;
            atomicMin(&fin[tok], p);
        }
    }
}

// -------------------------------------------------------------------------
// Kernel 4: gather winner, straight-through output, loss. One atomic/block.
// -------------------------------------------------------------------------
__global__ __launch_bounds__(256)
void finalize_kernel(const float* __restrict__ X, const float* __restrict__ C,
                     const unsigned long long* __restrict__ fin,
                     float* __restrict__ out)
{
    __shared__ float part[4];
    const int lane = threadIdx.x & 63;
    const int wv   = threadIdx.x >> 6;
    const int t0   = blockIdx.x * 64;

    float local = 0.f;
    for (int it = 0; it < 16; ++it) {
        const int t = t0 + wv * 16 + it;
        const unsigned code = (unsigned)(fin[t] & 0xFFFFFFFFull);
        float4 c4 = *(const float4*)&C[(size_t)code * DIMD + lane * 4];
        float4 x4 = *(const float4*)&X[(size_t)t * DIMD + lane * 4];
        float4 w  = {c4.x - x4.x, c4.y - x4.y, c4.z - x4.z, c4.w - x4.w};
        local += w.x * w.x + w.y * w.y + w.z * w.z + w.w * w.w;
        float4 zq = {x4.x + w.x, x4.y + w.y, x4.z + w.z, x4.w + w.w};
        *(float4*)&out[(size_t)t * DIMD + lane * 4] = zq;
        if (lane == 0) out[NELEM + 1 + t] = (float)code;
    }
#pragma unroll
    for (int off = 1; off < 64; off <<= 1) local += __shfl_xor(local, off);
    if (lane == 0) part[wv] = local;
    __syncthreads();
    if (threadIdx.x == 0) {
        const float s = part[0] + part[1] + part[2] + part[3];
        atomicAdd(&out[NELEM], s * (1.25f / (float)NELEM));
    }
}

// -------------------------------------------------------------------------
extern "C" void kernel_launch(void* const* d_in, const int* in_sizes, int n_in,
                              void* d_out, int out_size, void* d_ws, size_t ws_size,
                              hipStream_t stream)
{
    const float* X = (const float*)d_in[0];
    const float* E = (const float*)d_in[1];
    const float* W = (const float*)d_in[2];
    const float* b = (const float*)d_in[3];
    float* out = (float*)d_out;

    char* w = (char*)d_ws;
    float* C            = (float*)w;           w += (size_t)NCODE * DIMD * 4;
    unsigned short* Xb  = (unsigned short*)w;  w += (size_t)NTOK * DIMD * 2;
    unsigned short* Cb2 = (unsigned short*)w;  w += (size_t)NCODE * DIMD * 2;
    float* xnorm        = (float*)w;           w += (size_t)NTOK * 4;
    float* cnormA       = (float*)w;           w += (size_t)NCODE * 4;
    float* cnormB       = (float*)w;           w += (size_t)NCODE * 4;
    unsigned* cnt       = (unsigned*)w;        w += 256;
    unsigned long long* fin = (unsigned long long*)w; w += (size_t)NTOK * 8;
    unsigned* minkey    = (unsigned*)w;        w += (size_t)NTOK * 4;
    unsigned* list      = (unsigned*)w;

    size_t used = (size_t)(w - (char*)d_ws);
    size_t avail = (ws_size > used) ? (ws_size - used) / 4 : 0;
    unsigned cap = (unsigned)((avail > 16777216u) ? 16777216u : avail);

    // 5 dispatches, zero memsets.
    prep_kernel<<<PROJ_BLOCKS + CONV_BLOCKS, 256, 0, stream>>>(
        E, W, b, C, Cb2, cnormA, cnormB, X, xnorm, Xb, fin, minkey, cnt, out);
    dist_min_kernel<<<dim3(NTOK / TOK_PER_BLOCK, NCODE / CODES_PER_BLOCK), 256, 0, stream>>>(
        Xb, Cb2, cnormA, cnormB, minkey);
    dist_emit_kernel<<<dim3(NTOK / 64, EM_SPLITS), 256, 0, stream>>>(
        Xb, Cb2, cnormA, cnormB, minkey, list, cnt, cap);
    rescore_kernel<<<1024, 256, 0, stream>>>(X, C, xnorm, cnormA, cnormB, list, cnt, cap, fin);
    finalize_kernel<<<NTOK / 64, 256, 0, stream>>>(X, C, fin, out);
}

// Round 13
// 268.490 us; speedup vs baseline: 1.1549x; 1.0175x over previous
//
#include <hip/hip_runtime.h>

// Problem constants
#define DIMD   256
#define NTOK   16384
#define NCODE  8192
#define NELEM  (NTOK * DIMD)

// fp32 project-GEMM tiling
#define BM 128
#define BK 128
#define BD 32
#define PAD 4
#define LDS_STRIDE (BM + PAD)

// distance kernels — per-pass measured-best structures:
//   dist_min : shared-B (R10) — 4 waves share a 1024-code slice, B DMA'd
//              to LDS dbuf, 1 barrier/group. Divergence-free -> barrier
//              cheap, B L2 traffic /4.
//   dist_emit: private-B (R9) — per-wave register B-dbuf, barrier-free
//              (divergence-tolerant). R13: EM_SPLITS 4->2 — 512 blocks =
//              ONE occupancy round (was 2), A-fragment reload traffic /2.
// Dead ends (measured): forced occupancy (R1 spills), fused emission
//   (R0/2/3), device atomics in loop (R4: 425us), acc-split ILP (R6
//   spills), 32-tok/wave (R7 halves intensity), per-wave async LDS (R8),
//   shared-B emit (R10: barriers amplify emission divergence),
//   cooperative grid-sync fusion (R12: hipLaunchCooperativeKernel
//   core-dumps under the harness's graph capture — DO NOT USE).
#define MARGIN 0.5f                   // > two-sided worst-case bf16 distance error
#define EBUF_CAP 1024                 // per-block emit staging

// shared-B (min) geometry
#define CODES_PER_BLOCK 1024
#define TOK_PER_BLOCK   256
#define MIN_NGROUPS (CODES_PER_BLOCK / 16)      // 64
// private-B (emit) geometry
#define EM_SPLITS 2
#define EM_CPW (NCODE / EM_SPLITS / 4)          // 1024
#define EM_NGROUPS (EM_CPW / 16)                // 64

#define PROJ_BLOCKS ((NCODE / BM) * (DIMD / BK))   // 128
#define CONV_BLOCKS (NTOK / 4)                     // 4096

typedef float floatx4 __attribute__((ext_vector_type(4)));
typedef short short8  __attribute__((ext_vector_type(8)));
typedef unsigned int u32;

__device__ __forceinline__ unsigned short f2bf(float f) {
    unsigned u = __float_as_uint(f);
    unsigned r = (u + 0x7FFFu + ((u >> 16) & 1u)) >> 16;
    return (unsigned short)r;
}

// async 16B/lane global->LDS DMA: dest = wave-uniform base + lane*16 (linear)
__device__ __forceinline__ void gl_lds16(const void* g, void* l) {
    __builtin_amdgcn_global_load_lds(
        (const __attribute__((address_space(1))) u32*)g,
        (__attribute__((address_space(3))) u32*)l, 16, 0, 0);
}

// monotone float<->uint key (handles negative partial distances)
__device__ __forceinline__ unsigned fkey(float f) {
    unsigned u = __float_as_uint(f);
    return (u & 0x80000000u) ? ~u : (u | 0x80000000u);
}
__device__ __forceinline__ float funkey(unsigned k) {
    unsigned u = (k & 0x80000000u) ? (k & 0x7FFFFFFFu) : ~k;
    return __uint_as_float(u);
}

// fragment-major Cb index for element (row=code, col=k):
// block (row/16, col/32) of 512 elems; within: lane=(colsub/8)*16+(row%16), elem=col%8
__device__ __forceinline__ size_t cb2_idx(int row, int col) {
    return ((size_t)((row >> 4) * 8 + (col >> 5))) * 512
         + (size_t)((((col >> 3) & 3) * 16 + (row & 15)) * 8 + (col & 7));
}

// -------------------------------------------------------------------------
// Kernel 1 (fused prep): blocks [0,128) = codebook projection; blocks
// [128, 128+4096) = convx + all buffer inits. (round-9 form, unchanged)
// -------------------------------------------------------------------------
__global__ __launch_bounds__(256, 3)
void prep_kernel(const float* __restrict__ E, const float* __restrict__ W,
                 const float* __restrict__ bias, float* __restrict__ C,
                 unsigned short* __restrict__ Cb2,
                 float* __restrict__ cnormA, float* __restrict__ cnormB,
                 const float* __restrict__ X, float* __restrict__ xnorm,
                 unsigned short* __restrict__ Xb,
                 unsigned long long* __restrict__ fin,
                 unsigned* __restrict__ minkey,
                 unsigned* __restrict__ cnt, float* __restrict__ out)
{
    __shared__ float smem[2 * BD * LDS_STRIDE];

    const int bid = blockIdx.x;
    const int tid = threadIdx.x;

    if (bid >= PROJ_BLOCKS) {
        // ---- convx part + inits ----
        const int row0 = (bid - PROJ_BLOCKS) * 4;
        const int wave = tid >> 6;
        const int lane = tid & 63;
        const int row  = row0 + wave;
        float4 v = *(const float4*)&X[(size_t)row * DIMD + lane * 4];
        ushort4 h = {f2bf(v.x), f2bf(v.y), f2bf(v.z), f2bf(v.w)};
        *(ushort4*)&Xb[(size_t)row * DIMD + lane * 4] = h;
        float s = v.x * v.x + v.y * v.y + v.z * v.z + v.w * v.w;
#pragma unroll
        for (int off = 1; off < 64; off <<= 1) s += __shfl_xor(s, off);
        if (lane == 0) xnorm[row] = s;
        if (tid < 4) {
            fin[row0 + tid]    = ~0ull;
            minkey[row0 + tid] = ~0u;
        }
        if (bid == PROJ_BLOCKS && tid == 0) { *cnt = 0; out[NELEM] = 0.f; }
        return;
    }

    // ---- project part ----
    float* As = smem;
    float* Bs = smem + BD * LDS_STRIDE;

    const int tx  = tid & 15;
    const int ty  = tid >> 4;
    const int m0  = (bid & 63) * BM;
    const int j0  = (bid >> 6) * BK;

    const int srow = tid >> 3;
    const int scol = (tid & 7) * 4;

    float acc[8][8];
#pragma unroll
    for (int i = 0; i < 8; ++i)
#pragma unroll
        for (int j = 0; j < 8; ++j) acc[i][j] = 0.f;

    for (int dc = 0; dc < DIMD / BD; ++dc) {
        const int d0 = dc * BD;
        __syncthreads();
#pragma unroll
        for (int rr = 0; rr < 4; ++rr) {
            const int r = srow + rr * 32;
            float4 av = *(const float4*)&E[(size_t)(m0 + r) * DIMD + d0 + scol];
            As[(scol + 0) * LDS_STRIDE + r] = av.x;
            As[(scol + 1) * LDS_STRIDE + r] = av.y;
            As[(scol + 2) * LDS_STRIDE + r] = av.z;
            As[(scol + 3) * LDS_STRIDE + r] = av.w;
            float4 bv = *(const float4*)&W[(size_t)(j0 + r) * DIMD + d0 + scol];
            Bs[(scol + 0) * LDS_STRIDE + r] = bv.x;
            Bs[(scol + 1) * LDS_STRIDE + r] = bv.y;
            Bs[(scol + 2) * LDS_STRIDE + r] = bv.z;
            Bs[(scol + 3) * LDS_STRIDE + r] = bv.w;
        }
        __syncthreads();
#pragma unroll 4
        for (int d = 0; d < BD; ++d) {
            float4 a0 = *(float4*)&As[d * LDS_STRIDE + ty * 4];
            float4 a1 = *(float4*)&As[d * LDS_STRIDE + 64 + ty * 4];
            float4 b0 = *(float4*)&Bs[d * LDS_STRIDE + tx * 4];
            float4 b1 = *(float4*)&Bs[d * LDS_STRIDE + 64 + tx * 4];
            float a[8] = {a0.x, a0.y, a0.z, a0.w, a1.x, a1.y, a1.z, a1.w};
            float b[8] = {b0.x, b0.y, b0.z, b0.w, b1.x, b1.y, b1.z, b1.w};
#pragma unroll
            for (int i = 0; i < 8; ++i)
#pragma unroll
                for (int j = 0; j < 8; ++j) acc[i][j] = fmaf(a[i], b[j], acc[i][j]);
        }
    }

    __syncthreads();                       // done reading As/Bs; reuse smem
    float* red = smem;                     // [128 rows][16 tx]

    float4 bja = *(const float4*)&bias[j0 + tx * 4];
    float4 bjb = *(const float4*)&bias[j0 + 64 + tx * 4];
#pragma unroll
    for (int i = 0; i < 8; ++i) {
        const int mloc = (i < 4) ? (ty * 4 + i) : (64 + ty * 4 + (i - 4));
        const int row  = m0 + mloc;
        const size_t rbase = (size_t)row * DIMD;
        float o[8] = {acc[i][0] + bja.x, acc[i][1] + bja.y, acc[i][2] + bja.z, acc[i][3] + bja.w,
                      acc[i][4] + bjb.x, acc[i][5] + bjb.y, acc[i][6] + bjb.z, acc[i][7] + bjb.w};
        *(float4*)&C[rbase + j0 + tx * 4]      = *(float4*)&o[0];
        *(float4*)&C[rbase + j0 + 64 + tx * 4] = *(float4*)&o[4];
        ushort4 h0 = {f2bf(o[0]), f2bf(o[1]), f2bf(o[2]), f2bf(o[3])};
        ushort4 h1 = {f2bf(o[4]), f2bf(o[5]), f2bf(o[6]), f2bf(o[7])};
        *(ushort4*)&Cb2[cb2_idx(row, j0 + tx * 4)]      = h0;
        *(ushort4*)&Cb2[cb2_idx(row, j0 + 64 + tx * 4)] = h1;
        float p = 0.f;
#pragma unroll
        for (int j = 0; j < 8; ++j) p = fmaf(o[j], o[j], p);
        red[mloc * 16 + tx] = p;
    }
    __syncthreads();
    if (tid < 128) {
        float s = 0.f;
#pragma unroll
        for (int k = 0; k < 16; ++k) s += red[tid * 16 + k];
        float* dst = (j0 == 0) ? cnormA : cnormB;
        dst[m0 + tid] = s;                 // plain store, per-(block,row) unique
    }
}

// -------------------------------------------------------------------------
// Kernel 2a: PASS 1 — min-GEMM, SHARED-B (R10 measured-best form).
// 4 waves × 64 tokens scan the same 1024-code slice; B group (8KB) DMA'd
// into LDS double-buffer, one __syncthreads per group. Direct atomicMin.
// -------------------------------------------------------------------------
__global__ __launch_bounds__(256, 2)
void dist_min_kernel(const unsigned short* __restrict__ Xb,
                     const unsigned short* __restrict__ Cb2,
                     const float* __restrict__ cnormA,
                     const float* __restrict__ cnormB,
                     unsigned* __restrict__ minkey)
{
    __shared__ short Bls[2][4096];             // 16 KB double buffer
    __shared__ float cnl[CODES_PER_BLOCK];     // 4 KB

    const int tid  = threadIdx.x;
    const int lane = tid & 63;
    const int wv   = tid >> 6;
    const int l15  = lane & 15;
    const int quad = lane >> 4;
    const int tok0 = blockIdx.x * TOK_PER_BLOCK + wv * 64;
    const int cbase = blockIdx.y * CODES_PER_BLOCK;

    {
        const int t4 = tid * 4;
        float4 va = *(const float4*)&cnormA[cbase + t4];
        float4 vb = *(const float4*)&cnormB[cbase + t4];
        cnl[t4 + 0] = va.x + vb.x;
        cnl[t4 + 1] = va.y + vb.y;
        cnl[t4 + 2] = va.z + vb.z;
        cnl[t4 + 3] = va.w + vb.w;
    }

    const unsigned short* bsrc = Cb2 + (size_t)cbase * DIMD;
    auto STAGE = [&](int g) {
        const unsigned short* s = bsrc + (size_t)g * 4096 + wv * 1024 + lane * 8;
        short* d = &Bls[g & 1][wv * 1024];
        gl_lds16(s,       d);
        gl_lds16(s + 512, d + 512);
    };
    STAGE(0);
    STAGE(1);

    short8 a[4][8];
#pragma unroll
    for (int i = 0; i < 4; ++i) {
        const unsigned short* ap = Xb + (size_t)(tok0 + i * 16 + l15) * DIMD + quad * 8;
#pragma unroll
        for (int ks = 0; ks < 8; ++ks)
            a[i][ks] = *(const short8*)(ap + ks * 32);
    }

    float runv[16];
#pragma unroll
    for (int s = 0; s < 16; ++s) runv[s] = 3.4e38f;

    __syncthreads();   // cnl + staged groups 0,1 complete

    for (int g = 0; g < MIN_NGROUPS; ++g) {
        const short* bp = &Bls[g & 1][lane * 8];
        short8 bc[8];
#pragma unroll
        for (int ks = 0; ks < 8; ++ks) bc[ks] = *(const short8*)(bp + ks * 512);
        const float cnc = cnl[g * 16 + l15];

        floatx4 acc[4];
#pragma unroll
        for (int i = 0; i < 4; ++i) acc[i] = (floatx4){0.f, 0.f, 0.f, 0.f};
#pragma unroll
        for (int ks = 0; ks < 8; ++ks)
#pragma unroll
            for (int i = 0; i < 4; ++i)
                acc[i] = __builtin_amdgcn_mfma_f32_16x16x32_bf16(a[i][ks], bc[ks], acc[i], 0, 0, 0);

#pragma unroll
        for (int i = 0; i < 4; ++i)
#pragma unroll
            for (int r = 0; r < 4; ++r)
                runv[i * 4 + r] = fminf(runv[i * 4 + r], fmaf(-2.f, acc[i][r], cnc));

        __syncthreads();
        if (g + 2 < MIN_NGROUPS) STAGE(g + 2);
    }

#pragma unroll
    for (int s = 0; s < 16; ++s) {
        float m = runv[s];
#pragma unroll
        for (int off = 1; off < 16; off <<= 1) m = fminf(m, __shfl_xor(m, off));
        runv[s] = m;
    }
    if (l15 == 0) {
#pragma unroll
        for (int i = 0; i < 4; ++i)
#pragma unroll
            for (int r = 0; r < 4; ++r)
                atomicMin(&minkey[tok0 + i * 16 + quad * 4 + r], fkey(runv[i * 4 + r]));
    }
}

// -------------------------------------------------------------------------
// Kernel 2b: PASS 2 — emit vs FINAL threshold, PRIVATE-B register-dbuf
// (R9 measured-best form: barrier-free, divergence-tolerant). R13: each
// wave scans 1024 codes (EM_SPLITS=2) -> 512 blocks, one occupancy round,
// A-fragments loaded 2x total instead of 4x. Rare hits staged in block
// LDS; ONE device atomic per block.
// -------------------------------------------------------------------------
__global__ __launch_bounds__(256, 2)
void dist_emit_kernel(const unsigned short* __restrict__ Xb,
                      const unsigned short* __restrict__ Cb2,
                      const float* __restrict__ cnormA,
                      const float* __restrict__ cnormB,
                      const unsigned* __restrict__ minkey,
                      unsigned* __restrict__ list, unsigned* __restrict__ count,
                      unsigned cap)
{
    __shared__ float tokthr[64];
    __shared__ unsigned ebuf[EBUF_CAP];
    __shared__ unsigned ecnt, gbase;

    const int tid  = threadIdx.x;
    const int lane = tid & 63;
    const int wv   = tid >> 6;
    const int l15  = lane & 15;
    const int quad = lane >> 4;
    const int tok0 = blockIdx.x * 64;
    const int cbase = blockIdx.y * (NCODE / EM_SPLITS) + wv * EM_CPW;

    if (tid == 0) ecnt = 0;
    if (tid < 64) tokthr[tid] = funkey(minkey[tok0 + tid]) + MARGIN;
    __syncthreads();

    short8 a[4][8];
#pragma unroll
    for (int i = 0; i < 4; ++i) {
        const unsigned short* ap = Xb + (size_t)(tok0 + i * 16 + l15) * DIMD + quad * 8;
#pragma unroll
        for (int ks = 0; ks < 8; ++ks)
            a[i][ks] = *(const short8*)(ap + ks * 32);
    }

    float thr[16];
#pragma unroll
    for (int i = 0; i < 4; ++i)
#pragma unroll
        for (int r = 0; r < 4; ++r)
            thr[i * 4 + r] = tokthr[i * 16 + quad * 4 + r];

    const unsigned short* bp0 = Cb2 + (size_t)cbase * DIMD + lane * 8;

    short8 breg[2][8];
    float  cnr[2];
#pragma unroll
    for (int ks = 0; ks < 8; ++ks) breg[0][ks] = *(const short8*)(bp0 + ks * 512);
    cnr[0] = cnormA[cbase + l15] + cnormB[cbase + l15];

    auto group_body = [&](int g, short8 (&bc)[8], short8 (&bn)[8],
                          float cnc, float& cnn) {
        const int code0 = cbase + g * 16;
        if (g + 1 < EM_NGROUPS) {
            const unsigned short* bpn = bp0 + (size_t)(g + 1) * 4096;
#pragma unroll
            for (int ks = 0; ks < 8; ++ks) bn[ks] = *(const short8*)(bpn + ks * 512);
            const int cnx = code0 + 16 + l15;
            cnn = cnormA[cnx] + cnormB[cnx];
        }

        floatx4 acc[4];
#pragma unroll
        for (int i = 0; i < 4; ++i) acc[i] = (floatx4){0.f, 0.f, 0.f, 0.f};
#pragma unroll
        for (int ks = 0; ks < 8; ++ks)
#pragma unroll
            for (int i = 0; i < 4; ++i)
                acc[i] = __builtin_amdgcn_mfma_f32_16x16x32_bf16(a[i][ks], bc[ks], acc[i], 0, 0, 0);

        unsigned mask = 0;
#pragma unroll
        for (int i = 0; i < 4; ++i)
#pragma unroll
            for (int r = 0; r < 4; ++r) {
                const float dd = fmaf(-2.f, acc[i][r], cnc);
                if (dd < thr[i * 4 + r]) mask |= (1u << (i * 4 + r));
            }

        if (__any(mask != 0)) {
            if (mask) {
                unsigned pos = atomicAdd(&ecnt, (unsigned)__popc(mask));
#pragma unroll
                for (int i = 0; i < 4; ++i)
#pragma unroll
                    for (int r = 0; r < 4; ++r) {
                        const int s = i * 4 + r;
                        if (mask & (1u << s)) {
                            const unsigned token = tok0 + i * 16 + quad * 4 + r;
                            const unsigned entry = (token << 13) | (unsigned)(code0 + l15);
                            if (pos < EBUF_CAP) ebuf[pos] = entry;
                            else { unsigned gp = atomicAdd(count, 1u); if (gp < cap) list[gp] = entry; }
                            ++pos;
                        }
                    }
            }
        }
    };

    for (int gg = 0; gg < EM_NGROUPS; gg += 2) {
        group_body(gg,     breg[0], breg[1], cnr[0], cnr[1]);
        group_body(gg + 1, breg[1], breg[0], cnr[1], cnr[0]);
    }

    __syncthreads();
    const unsigned n = (ecnt < EBUF_CAP) ? ecnt : EBUF_CAP;
    if (tid == 0) gbase = atomicAdd(count, n);
    __syncthreads();
    const unsigned gb = gbase;
    for (unsigned i = tid; i < n; i += 256) {
        const unsigned p = gb + i;
        if (p < cap) list[p] = ebuf[i];
    }
}

// -------------------------------------------------------------------------
// Kernel 3: exact fp32 rescore. 16-lane groups, 4 candidates per wave.
// Packed (d_bits<<32 | code) atomicMin -> lowest-index tie-break.
// -------------------------------------------------------------------------
__global__ __launch_bounds__(256)
void rescore_kernel(const float* __restrict__ X, const float* __restrict__ C,
                    const float* __restrict__ xnorm,
                    const float* __restrict__ cnormA,
                    const float* __restrict__ cnormB,
                    const unsigned* __restrict__ list, const unsigned* __restrict__ count,
                    unsigned cap, unsigned long long* __restrict__ fin)
{
    const int lane = threadIdx.x & 63;
    const int g16  = lane & 15;
    const int sub  = lane >> 4;
    const int gid  = ((blockIdx.x * 256 + threadIdx.x) >> 6) * 4 + sub;
    const int ng   = ((gridDim.x * 256) >> 6) * 4;
    unsigned n = *count; if (n > cap) n = cap;

    for (unsigned c = gid; c < n; c += ng) {
        const unsigned e = list[c];
        const unsigned tok = e >> 13, code = e & 8191u;
        const float* xr = &X[(size_t)tok * DIMD];
        const float* cr = &C[(size_t)code * DIMD];
        float dot = 0.f;
#pragma unroll
        for (int r = 0; r < 4; ++r) {
            float4 x4 = *(const float4*)&xr[r * 64 + g16 * 4];
            float4 c4 = *(const float4*)&cr[r * 64 + g16 * 4];
            dot = fmaf(x4.x, c4.x, dot);
            dot = fmaf(x4.y, c4.y, dot);
            dot = fmaf(x4.z, c4.z, dot);
            dot = fmaf(x4.w, c4.w, dot);
        }
#pragma unroll
        for (int d = 1; d < 16; d <<= 1) dot += __shfl_xor(dot, d);
        if (g16 == 0) {
            const float dd = xnorm[tok] + (cnormA[code] + cnormB[code]) - 2.f * dot;
            const unsigned long long p =
                ((unsigned long long)__float_as_uint(dd) << 32) | code;
            atomicMin(&fin[tok], p);
        }
    }
}

// -------------------------------------------------------------------------
// Kernel 4: gather winner, straight-through output, loss. One atomic/block.
// -------------------------------------------------------------------------
__global__ __launch_bounds__(256)
void finalize_kernel(const float* __restrict__ X, const float* __restrict__ C,
                     const unsigned long long* __restrict__ fin,
                     float* __restrict__ out)
{
    __shared__ float part[4];
    const int lane = threadIdx.x & 63;
    const int wv   = threadIdx.x >> 6;
    const int t0   = blockIdx.x * 64;

    float local = 0.f;
    for (int it = 0; it < 16; ++it) {
        const int t = t0 + wv * 16 + it;
        const unsigned code = (unsigned)(fin[t] & 0xFFFFFFFFull);
        float4 c4 = *(const float4*)&C[(size_t)code * DIMD + lane * 4];
        float4 x4 = *(const float4*)&X[(size_t)t * DIMD + lane * 4];
        float4 w  = {c4.x - x4.x, c4.y - x4.y, c4.z - x4.z, c4.w - x4.w};
        local += w.x * w.x + w.y * w.y + w.z * w.z + w.w * w.w;
        float4 zq = {x4.x + w.x, x4.y + w.y, x4.z + w.z, x4.w + w.w};
        *(float4*)&out[(size_t)t * DIMD + lane * 4] = zq;
        if (lane == 0) out[NELEM + 1 + t] = (float)code;
    }
#pragma unroll
    for (int off = 1; off < 64; off <<= 1) local += __shfl_xor(local, off);
    if (lane == 0) part[wv] = local;
    __syncthreads();
    if (threadIdx.x == 0) {
        const float s = part[0] + part[1] + part[2] + part[3];
        atomicAdd(&out[NELEM], s * (1.25f / (float)NELEM));
    }
}

// -------------------------------------------------------------------------
extern "C" void kernel_launch(void* const* d_in, const int* in_sizes, int n_in,
                              void* d_out, int out_size, void* d_ws, size_t ws_size,
                              hipStream_t stream)
{
    const float* X = (const float*)d_in[0];
    const float* E = (const float*)d_in[1];
    const float* W = (const float*)d_in[2];
    const float* b = (const float*)d_in[3];
    float* out = (float*)d_out;

    char* w = (char*)d_ws;
    float* C            = (float*)w;           w += (size_t)NCODE * DIMD * 4;
    unsigned short* Xb  = (unsigned short*)w;  w += (size_t)NTOK * DIMD * 2;
    unsigned short* Cb2 = (unsigned short*)w;  w += (size_t)NCODE * DIMD * 2;
    float* xnorm        = (float*)w;           w += (size_t)NTOK * 4;
    float* cnormA       = (float*)w;           w += (size_t)NCODE * 4;
    float* cnormB       = (float*)w;           w += (size_t)NCODE * 4;
    unsigned* cnt       = (unsigned*)w;        w += 256;
    unsigned long long* fin = (unsigned long long*)w; w += (size_t)NTOK * 8;
    unsigned* minkey    = (unsigned*)w;        w += (size_t)NTOK * 4;
    unsigned* list      = (unsigned*)w;

    size_t used = (size_t)(w - (char*)d_ws);
    size_t avail = (ws_size > used) ? (ws_size - used) / 4 : 0;
    unsigned cap = (unsigned)((avail > 16777216u) ? 16777216u : avail);

    // 5 dispatches, zero memsets.
    prep_kernel<<<PROJ_BLOCKS + CONV_BLOCKS, 256, 0, stream>>>(
        E, W, b, C, Cb2, cnormA, cnormB, X, xnorm, Xb, fin, minkey, cnt, out);
    dist_min_kernel<<<dim3(NTOK / TOK_PER_BLOCK, NCODE / CODES_PER_BLOCK), 256, 0, stream>>>(
        Xb, Cb2, cnormA, cnormB, minkey);
    dist_emit_kernel<<<dim3(NTOK / 64, EM_SPLITS), 256, 0, stream>>>(
        Xb, Cb2, cnormA, cnormB, minkey, list, cnt, cap);
    rescore_kernel<<<1024, 256, 0, stream>>>(X, C, xnorm, cnormA, cnormB, list, cnt, cap, fin);
    finalize_kernel<<<NTOK / 64, 256, 0, stream>>>(X, C, fin, out);
}

// Round 14
// 267.276 us; speedup vs baseline: 1.1602x; 1.0045x over previous
//
#include <hip/hip_runtime.h>

// Problem constants
#define DIMD   256
#define NTOK   16384
#define NCODE  8192
#define NELEM  (NTOK * DIMD)

// fp32 project-GEMM tiling — R14: BM 128->64 (grid 128->256 blocks = 1/CU;
// project was running on HALF the machine at 128 blocks). Per-output
// d-accumulation order unchanged -> C bit-exact; cnormA/B structure kept.
#define PBM 64
#define PBK 128
#define BD 32
#define PAD 4
#define SA (PBM + PAD)    // A tile stride (col-major [col][row])
#define SB (PBK + PAD)    // B tile stride

// distance kernels — per-pass measured-best structures:
//   dist_min : shared-B (R10) — 4 waves share a 1024-code slice, B DMA'd
//              to LDS dbuf, 1 barrier/group (divergence-free).
//   dist_emit: private-B (R9/R13) — per-wave register B-dbuf, barrier-
//              free, EM_SPLITS=2 (512 blocks = one occupancy round).
// Dead ends (measured): forced occupancy (R1 spills), fused emission
//   (R0/2/3), device atomics in loop (R4: 425us), acc-split ILP (R6
//   spills), 32-tok/wave (R7 halves intensity), per-wave async LDS (R8),
//   shared-B emit (R10), cooperative grid-sync fusion (R12: core-dump
//   under harness graph capture — DO NOT USE).
#define MARGIN 0.5f                   // > two-sided worst-case bf16 distance error
#define EBUF_CAP 1024                 // per-block emit staging

// shared-B (min) geometry
#define CODES_PER_BLOCK 1024
#define TOK_PER_BLOCK   256
#define MIN_NGROUPS (CODES_PER_BLOCK / 16)      // 64
// private-B (emit) geometry
#define EM_SPLITS 2
#define EM_CPW (NCODE / EM_SPLITS / 4)          // 1024
#define EM_NGROUPS (EM_CPW / 16)                // 64

#define PROJ_BLOCKS ((NCODE / PBM) * (DIMD / PBK))   // 256
#define CONV_BLOCKS (NTOK / 4)                       // 4096

typedef float floatx4 __attribute__((ext_vector_type(4)));
typedef short short8  __attribute__((ext_vector_type(8)));
typedef unsigned int u32;

__device__ __forceinline__ unsigned short f2bf(float f) {
    unsigned u = __float_as_uint(f);
    unsigned r = (u + 0x7FFFu + ((u >> 16) & 1u)) >> 16;
    return (unsigned short)r;
}

// async 16B/lane global->LDS DMA: dest = wave-uniform base + lane*16 (linear)
__device__ __forceinline__ void gl_lds16(const void* g, void* l) {
    __builtin_amdgcn_global_load_lds(
        (const __attribute__((address_space(1))) u32*)g,
        (__attribute__((address_space(3))) u32*)l, 16, 0, 0);
}

// monotone float<->uint key (handles negative partial distances)
__device__ __forceinline__ unsigned fkey(float f) {
    unsigned u = __float_as_uint(f);
    return (u & 0x80000000u) ? ~u : (u | 0x80000000u);
}
__device__ __forceinline__ float funkey(unsigned k) {
    unsigned u = (k & 0x80000000u) ? (k & 0x7FFFFFFFu) : ~k;
    return __uint_as_float(u);
}

// fragment-major Cb index for element (row=code, col=k):
// block (row/16, col/32) of 512 elems; within: lane=(colsub/8)*16+(row%16), elem=col%8
__device__ __forceinline__ size_t cb2_idx(int row, int col) {
    return ((size_t)((row >> 4) * 8 + (col >> 5))) * 512
         + (size_t)((((col >> 3) & 3) * 16 + (row & 15)) * 8 + (col & 7));
}

// -------------------------------------------------------------------------
// Kernel 1 (fused prep): blocks [0,256) = codebook projection (64x128
// tiles, 256 blocks = 1/CU); blocks [256, 256+4096) = convx + inits.
// -------------------------------------------------------------------------
__global__ __launch_bounds__(256, 3)
void prep_kernel(const float* __restrict__ E, const float* __restrict__ W,
                 const float* __restrict__ bias, float* __restrict__ C,
                 unsigned short* __restrict__ Cb2,
                 float* __restrict__ cnormA, float* __restrict__ cnormB,
                 const float* __restrict__ X, float* __restrict__ xnorm,
                 unsigned short* __restrict__ Xb,
                 unsigned long long* __restrict__ fin,
                 unsigned* __restrict__ minkey,
                 unsigned* __restrict__ cnt, float* __restrict__ out)
{
    __shared__ float smem[BD * SA + BD * SB];   // 2176 + 4224 floats = 25.6 KB

    const int bid = blockIdx.x;
    const int tid = threadIdx.x;

    if (bid >= PROJ_BLOCKS) {
        // ---- convx part + inits ----
        const int row0 = (bid - PROJ_BLOCKS) * 4;
        const int wave = tid >> 6;
        const int lane = tid & 63;
        const int row  = row0 + wave;
        float4 v = *(const float4*)&X[(size_t)row * DIMD + lane * 4];
        ushort4 h = {f2bf(v.x), f2bf(v.y), f2bf(v.z), f2bf(v.w)};
        *(ushort4*)&Xb[(size_t)row * DIMD + lane * 4] = h;
        float s = v.x * v.x + v.y * v.y + v.z * v.z + v.w * v.w;
#pragma unroll
        for (int off = 1; off < 64; off <<= 1) s += __shfl_xor(s, off);
        if (lane == 0) xnorm[row] = s;
        if (tid < 4) {
            fin[row0 + tid]    = ~0ull;
            minkey[row0 + tid] = ~0u;
        }
        if (bid == PROJ_BLOCKS && tid == 0) { *cnt = 0; out[NELEM] = 0.f; }
        return;
    }

    // ---- project part: 64-row x 128-col tile ----
    float* As = smem;            // [32 cols][SA rows] col-major
    float* Bs = smem + BD * SA;  // [32 cols][SB rows]

    const int tx  = tid & 15;
    const int ty  = tid >> 4;
    const int m0  = (bid & 127) * PBM;
    const int j0  = (bid >> 7) * PBK;

    const int srow = tid >> 3;          // 0..31
    const int scol = (tid & 7) * 4;     // 0..28

    float acc[4][8];
#pragma unroll
    for (int i = 0; i < 4; ++i)
#pragma unroll
        for (int j = 0; j < 8; ++j) acc[i][j] = 0.f;

    for (int dc = 0; dc < DIMD / BD; ++dc) {
        const int d0 = dc * BD;
        __syncthreads();
        // A: 64 rows x 32 cols (2 passes of 32 rows)
#pragma unroll
        for (int rr = 0; rr < 2; ++rr) {
            const int r = srow + rr * 32;
            float4 av = *(const float4*)&E[(size_t)(m0 + r) * DIMD + d0 + scol];
            As[(scol + 0) * SA + r] = av.x;
            As[(scol + 1) * SA + r] = av.y;
            As[(scol + 2) * SA + r] = av.z;
            As[(scol + 3) * SA + r] = av.w;
        }
        // B: 128 rows x 32 cols (4 passes)
#pragma unroll
        for (int rr = 0; rr < 4; ++rr) {
            const int r = srow + rr * 32;
            float4 bv = *(const float4*)&W[(size_t)(j0 + r) * DIMD + d0 + scol];
            Bs[(scol + 0) * SB + r] = bv.x;
            Bs[(scol + 1) * SB + r] = bv.y;
            Bs[(scol + 2) * SB + r] = bv.z;
            Bs[(scol + 3) * SB + r] = bv.w;
        }
        __syncthreads();
#pragma unroll 4
        for (int d = 0; d < BD; ++d) {
            float4 a0 = *(float4*)&As[d * SA + ty * 4];
            float4 b0 = *(float4*)&Bs[d * SB + tx * 4];
            float4 b1 = *(float4*)&Bs[d * SB + 64 + tx * 4];
            float a[4] = {a0.x, a0.y, a0.z, a0.w};
            float b[8] = {b0.x, b0.y, b0.z, b0.w, b1.x, b1.y, b1.z, b1.w};
#pragma unroll
            for (int i = 0; i < 4; ++i)
#pragma unroll
                for (int j = 0; j < 8; ++j) acc[i][j] = fmaf(a[i], b[j], acc[i][j]);
        }
    }

    __syncthreads();                       // done reading As/Bs; reuse smem
    float* red = smem;                     // [64 rows][16 tx]

    float4 bja = *(const float4*)&bias[j0 + tx * 4];
    float4 bjb = *(const float4*)&bias[j0 + 64 + tx * 4];
#pragma unroll
    for (int i = 0; i < 4; ++i) {
        const int mloc = ty * 4 + i;
        const int row  = m0 + mloc;
        const size_t rbase = (size_t)row * DIMD;
        float o[8] = {acc[i][0] + bja.x, acc[i][1] + bja.y, acc[i][2] + bja.z, acc[i][3] + bja.w,
                      acc[i][4] + bjb.x, acc[i][5] + bjb.y, acc[i][6] + bjb.z, acc[i][7] + bjb.w};
        *(float4*)&C[rbase + j0 + tx * 4]      = *(float4*)&o[0];
        *(float4*)&C[rbase + j0 + 64 + tx * 4] = *(float4*)&o[4];
        ushort4 h0 = {f2bf(o[0]), f2bf(o[1]), f2bf(o[2]), f2bf(o[3])};
        ushort4 h1 = {f2bf(o[4]), f2bf(o[5]), f2bf(o[6]), f2bf(o[7])};
        *(ushort4*)&Cb2[cb2_idx(row, j0 + tx * 4)]      = h0;
        *(ushort4*)&Cb2[cb2_idx(row, j0 + 64 + tx * 4)] = h1;
        float p = 0.f;
#pragma unroll
        for (int j = 0; j < 8; ++j) p = fmaf(o[j], o[j], p);
        red[mloc * 16 + tx] = p;
    }
    __syncthreads();
    if (tid < 64) {
        float s = 0.f;
#pragma unroll
        for (int k = 0; k < 16; ++k) s += red[tid * 16 + k];
        float* dst = (j0 == 0) ? cnormA : cnormB;
        dst[m0 + tid] = s;                 // plain store, per-(block,row) unique
    }
}

// -------------------------------------------------------------------------
// Kernel 2a: PASS 1 — min-GEMM, SHARED-B (R10 measured-best form).
// 4 waves × 64 tokens scan the same 1024-code slice; B group (8KB) DMA'd
// into LDS double-buffer, one __syncthreads per group. Direct atomicMin.
// -------------------------------------------------------------------------
__global__ __launch_bounds__(256, 2)
void dist_min_kernel(const unsigned short* __restrict__ Xb,
                     const unsigned short* __restrict__ Cb2,
                     const float* __restrict__ cnormA,
                     const float* __restrict__ cnormB,
                     unsigned* __restrict__ minkey)
{
    __shared__ short Bls[2][4096];             // 16 KB double buffer
    __shared__ float cnl[CODES_PER_BLOCK];     // 4 KB

    const int tid  = threadIdx.x;
    const int lane = tid & 63;
    const int wv   = tid >> 6;
    const int l15  = lane & 15;
    const int quad = lane >> 4;
    const int tok0 = blockIdx.x * TOK_PER_BLOCK + wv * 64;
    const int cbase = blockIdx.y * CODES_PER_BLOCK;

    {
        const int t4 = tid * 4;
        float4 va = *(const float4*)&cnormA[cbase + t4];
        float4 vb = *(const float4*)&cnormB[cbase + t4];
        cnl[t4 + 0] = va.x + vb.x;
        cnl[t4 + 1] = va.y + vb.y;
        cnl[t4 + 2] = va.z + vb.z;
        cnl[t4 + 3] = va.w + vb.w;
    }

    const unsigned short* bsrc = Cb2 + (size_t)cbase * DIMD;
    auto STAGE = [&](int g) {
        const unsigned short* s = bsrc + (size_t)g * 4096 + wv * 1024 + lane * 8;
        short* d = &Bls[g & 1][wv * 1024];
        gl_lds16(s,       d);
        gl_lds16(s + 512, d + 512);
    };
    STAGE(0);
    STAGE(1);

    short8 a[4][8];
#pragma unroll
    for (int i = 0; i < 4; ++i) {
        const unsigned short* ap = Xb + (size_t)(tok0 + i * 16 + l15) * DIMD + quad * 8;
#pragma unroll
        for (int ks = 0; ks < 8; ++ks)
            a[i][ks] = *(const short8*)(ap + ks * 32);
    }

    float runv[16];
#pragma unroll
    for (int s = 0; s < 16; ++s) runv[s] = 3.4e38f;

    __syncthreads();   // cnl + staged groups 0,1 complete

    for (int g = 0; g < MIN_NGROUPS; ++g) {
        const short* bp = &Bls[g & 1][lane * 8];
        short8 bc[8];
#pragma unroll
        for (int ks = 0; ks < 8; ++ks) bc[ks] = *(const short8*)(bp + ks * 512);
        const float cnc = cnl[g * 16 + l15];

        floatx4 acc[4];
#pragma unroll
        for (int i = 0; i < 4; ++i) acc[i] = (floatx4){0.f, 0.f, 0.f, 0.f};
#pragma unroll
        for (int ks = 0; ks < 8; ++ks)
#pragma unroll
            for (int i = 0; i < 4; ++i)
                acc[i] = __builtin_amdgcn_mfma_f32_16x16x32_bf16(a[i][ks], bc[ks], acc[i], 0, 0, 0);

#pragma unroll
        for (int i = 0; i < 4; ++i)
#pragma unroll
            for (int r = 0; r < 4; ++r)
                runv[i * 4 + r] = fminf(runv[i * 4 + r], fmaf(-2.f, acc[i][r], cnc));

        __syncthreads();
        if (g + 2 < MIN_NGROUPS) STAGE(g + 2);
    }

#pragma unroll
    for (int s = 0; s < 16; ++s) {
        float m = runv[s];
#pragma unroll
        for (int off = 1; off < 16; off <<= 1) m = fminf(m, __shfl_xor(m, off));
        runv[s] = m;
    }
    if (l15 == 0) {
#pragma unroll
        for (int i = 0; i < 4; ++i)
#pragma unroll
            for (int r = 0; r < 4; ++r)
                atomicMin(&minkey[tok0 + i * 16 + quad * 4 + r], fkey(runv[i * 4 + r]));
    }
}

// -------------------------------------------------------------------------
// Kernel 2b: PASS 2 — emit vs FINAL threshold, PRIVATE-B register-dbuf
// (R9/R13 measured-best form: barrier-free, EM_SPLITS=2 -> one occupancy
// round). Rare hits staged in block LDS; ONE device atomic per block.
// -------------------------------------------------------------------------
__global__ __launch_bounds__(256, 2)
void dist_emit_kernel(const unsigned short* __restrict__ Xb,
                      const unsigned short* __restrict__ Cb2,
                      const float* __restrict__ cnormA,
                      const float* __restrict__ cnormB,
                      const unsigned* __restrict__ minkey,
                      unsigned* __restrict__ list, unsigned* __restrict__ count,
                      unsigned cap)
{
    __shared__ float tokthr[64];
    __shared__ unsigned ebuf[EBUF_CAP];
    __shared__ unsigned ecnt, gbase;

    const int tid  = threadIdx.x;
    const int lane = tid & 63;
    const int wv   = tid >> 6;
    const int l15  = lane & 15;
    const int quad = lane >> 4;
    const int tok0 = blockIdx.x * 64;
    const int cbase = blockIdx.y * (NCODE / EM_SPLITS) + wv * EM_CPW;

    if (tid == 0) ecnt = 0;
    if (tid < 64) tokthr[tid] = funkey(minkey[tok0 + tid]) + MARGIN;
    __syncthreads();

    short8 a[4][8];
#pragma unroll
    for (int i = 0; i < 4; ++i) {
        const unsigned short* ap = Xb + (size_t)(tok0 + i * 16 + l15) * DIMD + quad * 8;
#pragma unroll
        for (int ks = 0; ks < 8; ++ks)
            a[i][ks] = *(const short8*)(ap + ks * 32);
    }

    float thr[16];
#pragma unroll
    for (int i = 0; i < 4; ++i)
#pragma unroll
        for (int r = 0; r < 4; ++r)
            thr[i * 4 + r] = tokthr[i * 16 + quad * 4 + r];

    const unsigned short* bp0 = Cb2 + (size_t)cbase * DIMD + lane * 8;

    short8 breg[2][8];
    float  cnr[2];
#pragma unroll
    for (int ks = 0; ks < 8; ++ks) breg[0][ks] = *(const short8*)(bp0 + ks * 512);
    cnr[0] = cnormA[cbase + l15] + cnormB[cbase + l15];

    auto group_body = [&](int g, short8 (&bc)[8], short8 (&bn)[8],
                          float cnc, float& cnn) {
        const int code0 = cbase + g * 16;
        if (g + 1 < EM_NGROUPS) {
            const unsigned short* bpn = bp0 + (size_t)(g + 1) * 4096;
#pragma unroll
            for (int ks = 0; ks < 8; ++ks) bn[ks] = *(const short8*)(bpn + ks * 512);
            const int cnx = code0 + 16 + l15;
            cnn = cnormA[cnx] + cnormB[cnx];
        }

        floatx4 acc[4];
#pragma unroll
        for (int i = 0; i < 4; ++i) acc[i] = (floatx4){0.f, 0.f, 0.f, 0.f};
#pragma unroll
        for (int ks = 0; ks < 8; ++ks)
#pragma unroll
            for (int i = 0; i < 4; ++i)
                acc[i] = __builtin_amdgcn_mfma_f32_16x16x32_bf16(a[i][ks], bc[ks], acc[i], 0, 0, 0);

        unsigned mask = 0;
#pragma unroll
        for (int i = 0; i < 4; ++i)
#pragma unroll
            for (int r = 0; r < 4; ++r) {
                const float dd = fmaf(-2.f, acc[i][r], cnc);
                if (dd < thr[i * 4 + r]) mask |= (1u << (i * 4 + r));
            }

        if (__any(mask != 0)) {
            if (mask) {
                unsigned pos = atomicAdd(&ecnt, (unsigned)__popc(mask));
#pragma unroll
                for (int i = 0; i < 4; ++i)
#pragma unroll
                    for (int r = 0; r < 4; ++r) {
                        const int s = i * 4 + r;
                        if (mask & (1u << s)) {
                            const unsigned token = tok0 + i * 16 + quad * 4 + r;
                            const unsigned entry = (token << 13) | (unsigned)(code0 + l15);
                            if (pos < EBUF_CAP) ebuf[pos] = entry;
                            else { unsigned gp = atomicAdd(count, 1u); if (gp < cap) list[gp] = entry; }
                            ++pos;
                        }
                    }
            }
        }
    };

    for (int gg = 0; gg < EM_NGROUPS; gg += 2) {
        group_body(gg,     breg[0], breg[1], cnr[0], cnr[1]);
        group_body(gg + 1, breg[1], breg[0], cnr[1], cnr[0]);
    }

    __syncthreads();
    const unsigned n = (ecnt < EBUF_CAP) ? ecnt : EBUF_CAP;
    if (tid == 0) gbase = atomicAdd(count, n);
    __syncthreads();
    const unsigned gb = gbase;
    for (unsigned i = tid; i < n; i += 256) {
        const unsigned p = gb + i;
        if (p < cap) list[p] = ebuf[i];
    }
}

// -------------------------------------------------------------------------
// Kernel 3: exact fp32 rescore. 16-lane groups, 4 candidates per wave.
// Packed (d_bits<<32 | code) atomicMin -> lowest-index tie-break.
// -------------------------------------------------------------------------
__global__ __launch_bounds__(256)
void rescore_kernel(const float* __restrict__ X, const float* __restrict__ C,
                    const float* __restrict__ xnorm,
                    const float* __restrict__ cnormA,
                    const float* __restrict__ cnormB,
                    const unsigned* __restrict__ list, const unsigned* __restrict__ count,
                    unsigned cap, unsigned long long* __restrict__ fin)
{
    const int lane = threadIdx.x & 63;
    const int g16  = lane & 15;
    const int sub  = lane >> 4;
    const int gid  = ((blockIdx.x * 256 + threadIdx.x) >> 6) * 4 + sub;
    const int ng   = ((gridDim.x * 256) >> 6) * 4;
    unsigned n = *count; if (n > cap) n = cap;

    for (unsigned c = gid; c < n; c += ng) {
        const unsigned e = list[c];
        const unsigned tok = e >> 13, code = e & 8191u;
        const float* xr = &X[(size_t)tok * DIMD];
        const float* cr = &C[(size_t)code * DIMD];
        float dot = 0.f;
#pragma unroll
        for (int r = 0; r < 4; ++r) {
            float4 x4 = *(const float4*)&xr[r * 64 + g16 * 4];
            float4 c4 = *(const float4*)&cr[r * 64 + g16 * 4];
            dot = fmaf(x4.x, c4.x, dot);
            dot = fmaf(x4.y, c4.y, dot);
            dot = fmaf(x4.z, c4.z, dot);
            dot = fmaf(x4.w, c4.w, dot);
        }
#pragma unroll
        for (int d = 1; d < 16; d <<= 1) dot += __shfl_xor(dot, d);
        if (g16 == 0) {
            const float dd = xnorm[tok] + (cnormA[code] + cnormB[code]) - 2.f * dot;
            const unsigned long long p =
                ((unsigned long long)__float_as_uint(dd) << 32) | code;
            atomicMin(&fin[tok], p);
        }
    }
}

// -------------------------------------------------------------------------
// Kernel 4: gather winner, straight-through output, loss. One atomic/block.
// -------------------------------------------------------------------------
__global__ __launch_bounds__(256)
void finalize_kernel(const float* __restrict__ X, const float* __restrict__ C,
                     const unsigned long long* __restrict__ fin,
                     float* __restrict__ out)
{
    __shared__ float part[4];
    const int lane = threadIdx.x & 63;
    const int wv   = threadIdx.x >> 6;
    const int t0   = blockIdx.x * 64;

    float local = 0.f;
    for (int it = 0; it < 16; ++it) {
        const int t = t0 + wv * 16 + it;
        const unsigned code = (unsigned)(fin[t] & 0xFFFFFFFFull);
        float4 c4 = *(const float4*)&C[(size_t)code * DIMD + lane * 4];
        float4 x4 = *(const float4*)&X[(size_t)t * DIMD + lane * 4];
        float4 w  = {c4.x - x4.x, c4.y - x4.y, c4.z - x4.z, c4.w - x4.w};
        local += w.x * w.x + w.y * w.y + w.z * w.z + w.w * w.w;
        float4 zq = {x4.x + w.x, x4.y + w.y, x4.z + w.z, x4.w + w.w};
        *(float4*)&out[(size_t)t * DIMD + lane * 4] = zq;
        if (lane == 0) out[NELEM + 1 + t] = (float)code;
    }
#pragma unroll
    for (int off = 1; off < 64; off <<= 1) local += __shfl_xor(local, off);
    if (lane == 0) part[wv] = local;
    __syncthreads();
    if (threadIdx.x == 0) {
        const float s = part[0] + part[1] + part[2] + part[3];
        atomicAdd(&out[NELEM], s * (1.25f / (float)NELEM));
    }
}

// -------------------------------------------------------------------------
extern "C" void kernel_launch(void* const* d_in, const int* in_sizes, int n_in,
                              void* d_out, int out_size, void* d_ws, size_t ws_size,
                              hipStream_t stream)
{
    const float* X = (const float*)d_in[0];
    const float* E = (const float*)d_in[1];
    const float* W = (const float*)d_in[2];
    const float* b = (const float*)d_in[3];
    float* out = (float*)d_out;

    char* w = (char*)d_ws;
    float* C            = (float*)w;           w += (size_t)NCODE * DIMD * 4;
    unsigned short* Xb  = (unsigned short*)w;  w += (size_t)NTOK * DIMD * 2;
    unsigned short* Cb2 = (unsigned short*)w;  w += (size_t)NCODE * DIMD * 2;
    float* xnorm        = (float*)w;           w += (size_t)NTOK * 4;
    float* cnormA       = (float*)w;           w += (size_t)NCODE * 4;
    float* cnormB       = (float*)w;           w += (size_t)NCODE * 4;
    unsigned* cnt       = (unsigned*)w;        w += 256;
    unsigned long long* fin = (unsigned long long*)w; w += (size_t)NTOK * 8;
    unsigned* minkey    = (unsigned*)w;        w += (size_t)NTOK * 4;
    unsigned* list      = (unsigned*)w;

    size_t used = (size_t)(w - (char*)d_ws);
    size_t avail = (ws_size > used) ? (ws_size - used) / 4 : 0;
    unsigned cap = (unsigned)((avail > 16777216u) ? 16777216u : avail);

    // 5 dispatches, zero memsets.
    prep_kernel<<<PROJ_BLOCKS + CONV_BLOCKS, 256, 0, stream>>>(
        E, W, b, C, Cb2, cnormA, cnormB, X, xnorm, Xb, fin, minkey, cnt, out);
    dist_min_kernel<<<dim3(NTOK / TOK_PER_BLOCK, NCODE / CODES_PER_BLOCK), 256, 0, stream>>>(
        Xb, Cb2, cnormA, cnormB, minkey);
    dist_emit_kernel<<<dim3(NTOK / 64, EM_SPLITS), 256, 0, stream>>>(
        Xb, Cb2, cnormA, cnormB, minkey, list, cnt, cap);
    rescore_kernel<<<1024, 256, 0, stream>>>(X, C, xnorm, cnormA, cnormB, list, cnt, cap, fin);
    finalize_kernel<<<NTOK / 64, 256, 0, stream>>>(X, C, fin, out);
}